// Round 18
// baseline (506.601 us; speedup 1.0000x reference)
//
#include <hip/hip_runtime.h>
#include <cstdint>

#define DV 2048
#define HH 16
#define DHD 128
#define LL 512
#define BB 2

typedef __attribute__((ext_vector_type(8))) short bf16x8;
typedef __attribute__((ext_vector_type(4))) float f32x4;
typedef __attribute__((ext_vector_type(4))) int i32x4;

typedef __attribute__((address_space(1))) const void* gas_cp;
typedef __attribute__((address_space(3))) void* las_p;

__device__ __forceinline__ void gll16(const void* g, void* l) {
    __builtin_amdgcn_global_load_lds((gas_cp)g, (las_p)l, 16, 0, 0);
}

__device__ __forceinline__ unsigned short f2b(float f) {
    union { float f; unsigned int u; } v; v.f = f;
    unsigned int u = v.u;
    return (unsigned short)((u + 0x7FFFu + ((u >> 16) & 1u)) >> 16);
}

// pack two f32 -> 2xbf16 in one u32 (v_cvt_pk_bf16_f32; no builtin on gfx950)
__device__ __forceinline__ unsigned int cvt_pk_bf16(float lo, float hi) {
    unsigned int r;
    asm("v_cvt_pk_bf16_f32 %0, %1, %2" : "=v"(r) : "v"(lo), "v"(hi));
    return r;
}

#if __has_builtin(__builtin_amdgcn_exp2f)
#define EX2(x) __builtin_amdgcn_exp2f(x)
#else
#define EX2(x) exp2f(x)
#endif

// ---------------- elementwise f32 -> bf16 ----------------
__global__ void cvt_k(const float* __restrict__ in, ushort* __restrict__ out, long n) {
    long stride = (long)gridDim.x * blockDim.x * 4;
    for (long i = ((long)blockIdx.x * blockDim.x + threadIdx.x) * 4; i < n; i += stride) {
        float4 f = *(const float4*)(in + i);
        *(ushort4*)(out + i) = make_ushort4(f2b(f.x), f2b(f.y), f2b(f.z), f2b(f.w));
    }
}

// ---------------- transpose + convert: out[c][r] = in[r][c] ----------------
__global__ void transpose_cvt_k(const float* __restrict__ in, ushort* __restrict__ outp,
                                int R, int C) {
    __shared__ float tile[64][65];
    int c0 = blockIdx.x * 64, r0 = blockIdx.y * 64;
    int tx = threadIdx.x & 63, ty = threadIdx.x >> 6;
#pragma unroll
    for (int p = 0; p < 16; ++p)
        tile[ty + p * 4][tx] = in[(long)(r0 + ty + p * 4) * C + c0 + tx];
    __syncthreads();
#pragma unroll
    for (int p = 0; p < 16; ++p)
        outp[(long)(c0 + ty + p * 4) * R + r0 + tx] = f2b(tile[tx][ty + p * 4]);
}

// ---------------- kv_cache -> c_kv out (f32) + bf16 copy ----------------
__global__ void kvcopy_k(const float* __restrict__ kv, float* __restrict__ cko,
                         ushort* __restrict__ ckb, int PAST, int T) {
    long n = (long)BB * PAST * LL;
    long pl2 = (long)PAST * LL;
    long stride = (long)gridDim.x * blockDim.x * 4;
    for (long i = ((long)blockIdx.x * blockDim.x + threadIdx.x) * 4; i < n; i += stride) {
        float4 f = *(const float4*)(kv + i);
        long b = i / pl2, wloc = i - b * pl2;
        long o = b * (long)T * LL + wloc;
        *(float4*)(cko + o) = f;
        *(ushort4*)(ckb + o) = make_ushort4(f2b(f.x), f2b(f.y), f2b(f.z), f2b(f.w));
    }
}

// ---------------- LayerNorm over L=512, one wave per row ----------------
__global__ __launch_bounds__(256) void ln_k(const float* __restrict__ cpre,
                                            const float* __restrict__ g, const float* __restrict__ be,
                                            float* __restrict__ cko, ushort* __restrict__ ckb,
                                            int S, int PAST, int T) {
    int wid = threadIdx.x >> 6, lane = threadIdx.x & 63;
    int row = blockIdx.x * 4 + wid;
    int b = row / S, s = row - b * S;
    const float* xr = cpre + (long)row * LL + lane * 8;
    float4 v0 = *(const float4*)xr;
    float4 v1 = *(const float4*)(xr + 4);
    float sum = v0.x + v0.y + v0.z + v0.w + v1.x + v1.y + v1.z + v1.w;
    float sq = v0.x * v0.x + v0.y * v0.y + v0.z * v0.z + v0.w * v0.w +
               v1.x * v1.x + v1.y * v1.y + v1.z * v1.z + v1.w * v1.w;
#pragma unroll
    for (int m = 1; m < 64; m <<= 1) { sum += __shfl_xor(sum, m, 64); sq += __shfl_xor(sq, m, 64); }
    float mu = sum * (1.0f / LL);
    float var = sq * (1.0f / LL) - mu * mu;
    float rstd = rsqrtf(var + 1e-5f);
    const float* gp = g + lane * 8;
    const float* bp = be + lane * 8;
    float4 g0 = *(const float4*)gp, g1 = *(const float4*)(gp + 4);
    float4 b0 = *(const float4*)bp, b1 = *(const float4*)(bp + 4);
    float y0 = (v0.x - mu) * rstd * g0.x + b0.x;
    float y1 = (v0.y - mu) * rstd * g0.y + b0.y;
    float y2 = (v0.z - mu) * rstd * g0.z + b0.z;
    float y3 = (v0.w - mu) * rstd * g0.w + b0.w;
    float y4 = (v1.x - mu) * rstd * g1.x + b1.x;
    float y5 = (v1.y - mu) * rstd * g1.y + b1.y;
    float y6 = (v1.z - mu) * rstd * g1.z + b1.z;
    float y7 = (v1.w - mu) * rstd * g1.w + b1.w;
    long o = ((long)b * T + PAST + s) * LL + lane * 8;
    *(float4*)(cko + o) = make_float4(y0, y1, y2, y3);
    *(float4*)(cko + o + 4) = make_float4(y4, y5, y6, y7);
    *(ushort4*)(ckb + o) = make_ushort4(f2b(y0), f2b(y1), f2b(y2), f2b(y3));
    *(ushort4*)(ckb + o + 4) = make_ushort4(f2b(y4), f2b(y5), f2b(y6), f2b(y7));
}

// ---------------- generic NT GEMM (r15 structure, occupancy 3) --------------
template <bool OUT_BF16>
__global__ __launch_bounds__(256, 3) void gemm_nt(const ushort* __restrict__ A,
                                                  const ushort* __restrict__ B,
                                                  void* __restrict__ Cv,
                                                  int K, int lda, int ldb, int ldc,
                                                  long aHi, long aLo, long bHi, long bLo,
                                                  long cHi, long cLo, int zdiv, float cscale) {
    __shared__ __align__(16) ushort Asm[128 * 72];
    __shared__ __align__(16) ushort Bsm[128 * 72];
    const int tid = threadIdx.x, wid = tid >> 6, lane = tid & 63;
    const int z = blockIdx.z, zh = z / zdiv, zl = z % zdiv;
    A += zh * aHi + zl * aLo;
    B += zh * bHi + zl * bLo;
    const long cOff = zh * cHi + zl * cLo;
    const int m0 = blockIdx.x * 128, n0 = blockIdx.y * 128;
    const int wm = (wid >> 1) * 64, wn = (wid & 1) * 64;
    f32x4 acc[4][4] = {};
    const int l8 = lane & 7;
    const int rowA = wid * 8 + (lane >> 3);
    const ushort* Ag = A + (long)(m0 + rowA) * lda + l8 * 8;
    const ushort* Bg = B + (long)(n0 + rowA) * ldb + l8 * 8;

    i32x4 ra[4], rb[4];
#pragma unroll
    for (int p = 0; p < 4; ++p) {
        ra[p] = *(const i32x4*)(Ag + (long)p * 32 * lda);
        rb[p] = *(const i32x4*)(Bg + (long)p * 32 * ldb);
    }
    for (int kt = 0; kt < K; kt += 64) {
        __syncthreads();
#pragma unroll
        for (int p = 0; p < 4; ++p) {
            *(i32x4*)(Asm + (p * 32 + rowA) * 72 + l8 * 8) = ra[p];
            *(i32x4*)(Bsm + (p * 32 + rowA) * 72 + l8 * 8) = rb[p];
        }
        __syncthreads();
        if (kt + 64 < K) {
#pragma unroll
            for (int p = 0; p < 4; ++p) {
                ra[p] = *(const i32x4*)(Ag + (long)p * 32 * lda + kt + 64);
                rb[p] = *(const i32x4*)(Bg + (long)p * 32 * ldb + kt + 64);
            }
        }
#pragma unroll
        for (int kk = 0; kk < 2; ++kk) {
            const int ko = kk * 32 + ((lane >> 4) << 3);
            bf16x8 af[4], bf[4];
#pragma unroll
            for (int i = 0; i < 4; ++i)
                af[i] = *(const bf16x8*)(Asm + (wm + i * 16 + (lane & 15)) * 72 + ko);
#pragma unroll
            for (int j = 0; j < 4; ++j)
                bf[j] = *(const bf16x8*)(Bsm + (wn + j * 16 + (lane & 15)) * 72 + ko);
#pragma unroll
            for (int i = 0; i < 4; ++i)
#pragma unroll
                for (int j = 0; j < 4; ++j)
                    acc[i][j] = __builtin_amdgcn_mfma_f32_16x16x32_bf16(af[i], bf[j], acc[i][j], 0, 0, 0);
        }
        __syncthreads();
    }
    const int cr = (lane >> 4) * 4, cc = lane & 15;
#pragma unroll
    for (int i = 0; i < 4; ++i) {
#pragma unroll
        for (int r = 0; r < 4; ++r) {
            const long row = m0 + wm + i * 16 + cr + r;
#pragma unroll
            for (int j = 0; j < 4; ++j) {
                const long col = n0 + wn + j * 16 + cc;
                if (OUT_BF16)
                    ((ushort*)Cv)[cOff + row * ldc + col] = f2b(acc[i][j][r] * cscale);
                else
                    ((float*)Cv)[cOff + row * ldc + col] = acc[i][j][r] * cscale;
            }
        }
    }
}

// ---------------- flash attention (round 18: 32 q/wave + paired lengths) -----
// d=128 MHA on khat/V. 4 waves x 32 q-rows = 128 q/block, 512 blocks (2/CU).
// Each K/V LDS fragment feeds TWO MFMAs -> LDS bytes/FLOP halved. CU pairing:
// same-CU blocks get complementary causal lengths (sblk = v vs 15-v) so per-CU
// work is constant (fixes r14's tail). 4-bit bufK swizzle (r17-verified).
#define PH_WAIT4()                                                  \
    do {                                                            \
        asm volatile("s_waitcnt vmcnt(4) lgkmcnt(0)" ::: "memory"); \
        __builtin_amdgcn_s_barrier();                               \
    } while (0)
#define PH_WAIT0()                                                  \
    do {                                                            \
        asm volatile("s_waitcnt vmcnt(0) lgkmcnt(0)" ::: "memory"); \
        __builtin_amdgcn_s_barrier();                               \
    } while (0)
#define RD_BAR()                                                    \
    do {                                                            \
        asm volatile("s_waitcnt lgkmcnt(0)" ::: "memory");          \
        __builtin_amdgcn_s_barrier();                               \
    } while (0)

__global__ __launch_bounds__(256) void attn_k(const ushort* __restrict__ qbf,
                                              const ushort* __restrict__ ktb,
                                              const ushort* __restrict__ vtb,
                                              ushort* __restrict__ ctxb,
                                              int S, int T, int PAST) {
    __shared__ __align__(16) ushort bufK[64 * 128];   // [t][d], 4-bit XOR-swizzled cols
    __shared__ __align__(16) ushort bufV[128 * 64];   // [d][t], 3-bit XOR-swizzled cols
    __shared__ __align__(16) ushort pl[4][32][64];    // per-wave P [q][t], t XOR-swizzled
    const int tid = threadIdx.x, wid = tid >> 6, lane = tid & 63;
    // XCD-chunked mapping with complementary-length CU pairing:
    // CU c on XCD x gets k=c and k=c+32 (same v=k&15, u differs) -> sblk v vs 15-v.
    const int nsb = S >> 7;               // 16 (128-row q blocks)
    const int id = (int)blockIdx.x;       // 0..511
    const int xcd = id & 7, k = id >> 3;  // k 0..63
    const int v = k & 15, u = k >> 4;     // u 0..3
    const int sblk = (u < 2) ? v : (15 - v);
    const int bh = xcd * 4 + u;           // 0..31
    const int h = bh & 15;
    const int b = bh >> 4;
    const int s0 = (nsb - 1 - sblk) * 128;

    const int g = lane >> 4, l15 = lane & 15, q8 = g << 3;
    const int swr = (l15 & 7) << 3;   // 3-bit read XOR (bufV / pl)
    const int swrK = l15 << 3;        // 4-bit read XOR (bufK)
    const int s0w = s0 + wid * 32;

    // Q fragments: 32 rows (aq*16 + l15) x 128 d; pinned in registers
    bf16x8 qf[8];  // [aq*4 + kk]
    {
        const ushort* qb = qbf + ((long)b * S + s0w + l15) * DV + h * DHD + q8;
#pragma unroll
        for (int aq = 0; aq < 2; ++aq)
#pragma unroll
            for (int kk = 0; kk < 4; ++kk)
                qf[aq * 4 + kk] = *(const bf16x8*)(qb + (long)aq * 16 * DV + kk * 32);
    }
#pragma unroll
    for (int i = 0; i < 8; ++i) asm volatile("" : "+v"(qf[i]));

    f32x4 cacc[2][4] = {};  // [aq][df 0..3]  d-low half
    f32x4 cacc2[2][4] = {}; // [aq][df] d-high half
    f32x4 sacc[2][4] = {};  // [aq][nf]: S^T[t=nf*16+g*4+r][q=aq*16+l15] (log2 domain)
    float mrow[2] = {-1e30f, -1e30f}, lrow[2] = {0.f, 0.f};
    const int rl = tid >> 4, cc16 = tid & 15;
    const int vr = tid >> 3, vc = tid & 7;
    const int ntile = (s0 + PAST) / 64 + 2;  // covers q up to s0+127
    const ushort* kbase = ktb + (long)b * T * DV + h * DHD;
    const ushort* vbase = vtb + ((long)b * DV + h * DHD) * T;
    const int kcol = (cc16 ^ rl) << 3;       // 4-bit pre-swizzled K source col
    const int vcol = (vc ^ (vr & 7)) << 3;   // 3-bit pre-swizzled V source col

    auto stageK = [&](int tt_) {
#pragma unroll
        for (int p = 0; p < 4; ++p)
            gll16(kbase + (long)(tt_ * 64 + p * 16 + rl) * DV + kcol, &bufK[p * 2048 + tid * 8]);
    };
    auto stageV = [&](int tt_) {
#pragma unroll
        for (int p = 0; p < 4; ++p)
            gll16(vbase + (long)(p * 32 + vr) * T + tt_ * 64 + vcol, &bufV[p * 2048 + tid * 8]);
    };

    stageK(0);
    stageV(0);

    for (int tt = 0; tt < ntile; ++tt) {
        const bool last = (tt == ntile - 1);
        const bool maskt = (tt >= ntile - 2);
        const int t0 = tt * 64;
        // ---- K(tt) ready; QK (swapped: out[t][q]); each K frag feeds 2 MFMAs ----
        PH_WAIT4();
        __builtin_amdgcn_s_setprio(1);
#pragma unroll
        for (int kk = 0; kk < 4; ++kk) {
            const int ko = kk * 32 + q8;
#pragma unroll
            for (int nf = 0; nf < 4; ++nf) {
                bf16x8 af = *(const bf16x8*)(&bufK[(nf * 16 + l15) * 128 + (ko ^ swrK)]);
                sacc[0][nf] = __builtin_amdgcn_mfma_f32_16x16x32_bf16(af, qf[kk], sacc[0][nf], 0, 0, 0);
                sacc[1][nf] = __builtin_amdgcn_mfma_f32_16x16x32_bf16(af, qf[4 + kk], sacc[1][nf], 0, 0, 0);
            }
        }
        __builtin_amdgcn_s_setprio(0);
        RD_BAR();                      // all waves done reading bufK
        if (!last) stageK(tt + 1);     // overwrite bufK with next K
        // ---- V(tt) ready ----
        if (last) { PH_WAIT0(); } else { PH_WAIT4(); }
        // ---- softmax (exp2 domain), per aq ----
#pragma unroll
        for (int aq = 0; aq < 2; ++aq) {
            float pm = -1e30f;
#pragma unroll
            for (int nf = 0; nf < 4; ++nf)
#pragma unroll
                for (int r = 0; r < 4; ++r) {
                    float vv = sacc[aq][nf][r];
                    if (maskt) {
                        int tg = t0 + nf * 16 + (g << 2) + r;
                        int qg = s0w + aq * 16 + l15;
                        if (tg > qg + PAST) vv = -1e30f;
                    }
                    sacc[aq][nf][r] = vv;
                    pm = fmaxf(pm, vv);
                }
            pm = fmaxf(pm, __shfl_xor(pm, 16, 64));
            pm = fmaxf(pm, __shfl_xor(pm, 32, 64));
            if (__any(pm > mrow[aq] + 11.5f)) {
                float mn = fmaxf(mrow[aq], pm);
                float al = EX2(mrow[aq] - mn);
                mrow[aq] = mn;
                lrow[aq] *= al;
#pragma unroll
                for (int r = 0; r < 4; ++r) {
                    float alr = __shfl(al, (g << 2) + r, 64);
#pragma unroll
                    for (int df = 0; df < 4; ++df) {
                        cacc[aq][df][r] *= alr;
                        cacc2[aq][df][r] *= alr;
                    }
                }
            }
            float ps = 0.f;
#pragma unroll
            for (int nf = 0; nf < 4; ++nf)
#pragma unroll
                for (int r = 0; r < 4; ++r) {
                    float p = EX2(sacc[aq][nf][r] - mrow[aq]);
                    sacc[aq][nf][r] = p;
                    ps += p;
                }
            ps += __shfl_xor(ps, 16, 64);
            ps += __shfl_xor(ps, 32, 64);
            lrow[aq] += ps;
            // P -> wave-private swizzled LDS, packed pairs
#pragma unroll
            for (int nf = 0; nf < 4; ++nf)
#pragma unroll
                for (int rp = 0; rp < 2; ++rp) {
                    unsigned int hb = cvt_pk_bf16(sacc[aq][nf][rp * 2], sacc[aq][nf][rp * 2 + 1]);
                    const int tlo = nf * 16 + (g << 2) + rp * 2;
                    *(unsigned int*)&pl[wid][aq * 16 + l15][tlo ^ swr] = hb;
                }
#pragma unroll
            for (int nf = 0; nf < 4; ++nf) sacc[aq][nf] = (f32x4){0.f, 0.f, 0.f, 0.f};
        }
        // ---- ctx += P * V : each V frag feeds 2 MFMAs (aq pair) ----
        __builtin_amdgcn_s_setprio(1);
#pragma unroll
        for (int kk = 0; kk < 2; ++kk) {
            bf16x8 a0 = *(const bf16x8*)(&pl[wid][l15][(kk * 32 + q8) ^ swr]);
            bf16x8 a1 = *(const bf16x8*)(&pl[wid][16 + l15][(kk * 32 + q8) ^ swr]);
#pragma unroll
            for (int df = 0; df < 4; ++df) {
                bf16x8 bv = *(const bf16x8*)(&bufV[(df * 16 + l15) * 64 + ((kk * 32 + q8) ^ swr)]);
                cacc[0][df] = __builtin_amdgcn_mfma_f32_16x16x32_bf16(a0, bv, cacc[0][df], 0, 0, 0);
                cacc[1][df] = __builtin_amdgcn_mfma_f32_16x16x32_bf16(a1, bv, cacc[1][df], 0, 0, 0);
            }
#pragma unroll
            for (int df = 0; df < 4; ++df) {
                bf16x8 bv = *(const bf16x8*)(&bufV[((df + 4) * 16 + l15) * 64 + ((kk * 32 + q8) ^ swr)]);
                cacc2[0][df] = __builtin_amdgcn_mfma_f32_16x16x32_bf16(a0, bv, cacc2[0][df], 0, 0, 0);
                cacc2[1][df] = __builtin_amdgcn_mfma_f32_16x16x32_bf16(a1, bv, cacc2[1][df], 0, 0, 0);
            }
        }
        __builtin_amdgcn_s_setprio(0);
        if (!last) {
            RD_BAR();                  // all waves done reading bufV
            stageV(tt + 1);
        }
    }
    // ---- epilogue: 32 q-rows x 128 d per wave ----
#pragma unroll
    for (int aq = 0; aq < 2; ++aq)
#pragma unroll
        for (int r = 0; r < 4; ++r) {
            float lr = __shfl(lrow[aq], (g << 2) + r, 64);
            float inv = 1.0f / lr;
            const long row = (long)b * S + s0w + aq * 16 + (g << 2) + r;
            const int d = h * DHD + l15;
#pragma unroll
            for (int df = 0; df < 4; ++df) {
                ctxb[row * DV + d + df * 16] = f2b(cacc[aq][df][r] * inv);
                ctxb[row * DV + d + (df + 4) * 16] = f2b(cacc2[aq][df][r] * inv);
            }
        }
}

extern "C" void kernel_launch(void* const* d_in, const int* in_sizes, int n_in,
                              void* d_out, int out_size, void* d_ws, size_t ws_size,
                              hipStream_t stream) {
    const float* x = (const float*)d_in[0];
    const float* kv = (const float*)d_in[1];
    const float* Wq = (const float*)d_in[2];
    const float* Wdkv = (const float*)d_in[3];
    const float* Wuk = (const float*)d_in[4];
    const float* Wuv = (const float*)d_in[5];
    const float* Wo = (const float*)d_in[6];
    const float* lng = (const float*)d_in[7];
    const float* lnbt = (const float*)d_in[8];
    const int S = in_sizes[0] / (BB * DV);     // 2048
    const int PAST = in_sizes[1] / (BB * LL);  // 2048
    const int T = S + PAST;                    // 4096

    float* out_p = (float*)d_out;                       // [B,S,D] f32
    float* ckv_out = out_p + (size_t)BB * S * DV;       // [B,T,L] f32

    char* w = (char*)d_ws;
    auto take = [&](size_t bytes) { char* p = w; w += (bytes + 255) & ~(size_t)255; return p; };
    ushort* xb    = (ushort*)take((size_t)BB * S * DV * 2);
    ushort* Wqb   = (ushort*)take((size_t)DV * DV * 2);
    ushort* WukT  = (ushort*)take((size_t)DV * LL * 2);   // [L][D] = Wuk^T
    ushort* Wdkvb = (ushort*)take((size_t)LL * DV * 2);
    ushort* Wuvb  = (ushort*)take((size_t)DV * LL * 2);
    ushort* Wob   = (ushort*)take((size_t)DV * DV * 2);
    ushort* absb  = (ushort*)take((size_t)DV * LL * 2);   // [D][L] = Wq@Wuk (scaled*log2e)
    float*  cpre  = (float*)take((size_t)BB * S * LL * 4);
    ushort* ckvb  = (ushort*)take((size_t)BB * T * LL * 2);
    ushort* vtb   = (ushort*)take((size_t)BB * DV * T * 2);  // [B][D][T]
    ushort* ktb   = (ushort*)take((size_t)BB * T * DV * 2);  // [B][T][D] khat
    ushort* ctxb  = (ushort*)take((size_t)BB * S * DV * 2);

    auto cvt = [&](const float* in, ushort* op, long n) {
        long nb = (n / 4 + 255) / 256;
        if (nb > 2048) nb = 2048;
        cvt_k<<<dim3((unsigned)nb), dim3(256), 0, stream>>>(in, op, n);
    };
    cvt(x, xb, (long)BB * S * DV);
    cvt(Wq, Wqb, (long)DV * DV);
    cvt(Wdkv, Wdkvb, (long)LL * DV);
    cvt(Wuv, Wuvb, (long)DV * LL);
    cvt(Wo, Wob, (long)DV * DV);
    transpose_cvt_k<<<dim3(LL / 64, DV / 64), dim3(256), 0, stream>>>(Wuk, WukT, DV, LL);
    kvcopy_k<<<dim3(2048), dim3(256), 0, stream>>>(kv, ckv_out, ckvb, PAST, T);

    // absorbed[j,l] = sum_i Wq[j,i]*Wuk[i,l], scaled by log2(e)/sqrt(dh) -> [D][L]
    gemm_nt<true><<<dim3(DV / 128, LL / 128, 1), dim3(256), 0, stream>>>(
        Wqb, WukT, absb, DV, DV, DV, LL, 0, 0, 0, 0, 0, 0, 1, 0.12751744900014818f);
    // c_pre = x * Wdkv^T  (f32)
    gemm_nt<false><<<dim3(BB * S / 128, LL / 128, 1), dim3(256), 0, stream>>>(
        xb, Wdkvb, cpre, DV, DV, DV, LL, 0, 0, 0, 0, 0, 0, 1, 1.0f);
    ln_k<<<dim3(BB * S / 4), dim3(256), 0, stream>>>(cpre, lng, lnbt, ckv_out, ckvb, S, PAST, T);
    // Vt[b] = Wuv * ckv[b]^T : [D][T] bf16
    gemm_nt<true><<<dim3(DV / 128, T / 128, BB), dim3(256), 0, stream>>>(
        Wuvb, ckvb, vtb, LL, LL, LL, T, 0, 0, (long)T * LL, 0, (long)DV * T, 0, 1, 1.0f);
    // khat[b] = ckv[b] @ absorbed^T : [T][D] bf16
    gemm_nt<true><<<dim3(T / 128, DV / 128, BB), dim3(256), 0, stream>>>(
        ckvb, absb, ktb, LL, LL, LL, DV, (long)T * LL, 0, 0, 0, (long)T * DV, 0, 1, 1.0f);
    // attention (d=128 MHA; Q = per-head slice of x)
    attn_k<<<dim3(BB * HH * (S / 128)), dim3(256), 0, stream>>>(xb, ktb, vtb, ctxb, S, T, PAST);
    // out = ctx * Wo^T (f32)
    gemm_nt<false><<<dim3(BB * S / 128, DV / 128, 1), dim3(256), 0, stream>>>(
        ctxb, Wob, out_p, DV, DV, DV, DV, 0, 0, 0, 0, 0, 0, 1, 1.0f);
}

// Round 19
// 346.419 us; speedup vs baseline: 1.4624x; 1.4624x over previous
//
#include <hip/hip_runtime.h>
#include <cstdint>

#define DV 2048
#define HH 16
#define DHD 128
#define LL 512
#define BB 2

typedef __attribute__((ext_vector_type(8))) short bf16x8;
typedef __attribute__((ext_vector_type(4))) float f32x4;
typedef __attribute__((ext_vector_type(4))) int i32x4;

typedef __attribute__((address_space(1))) const void* gas_cp;
typedef __attribute__((address_space(3))) void* las_p;

__device__ __forceinline__ void gll16(const void* g, void* l) {
    __builtin_amdgcn_global_load_lds((gas_cp)g, (las_p)l, 16, 0, 0);
}

__device__ __forceinline__ unsigned short f2b(float f) {
    union { float f; unsigned int u; } v; v.f = f;
    unsigned int u = v.u;
    return (unsigned short)((u + 0x7FFFu + ((u >> 16) & 1u)) >> 16);
}

// pack two f32 -> 2xbf16 in one u32 (v_cvt_pk_bf16_f32; no builtin on gfx950)
__device__ __forceinline__ unsigned int cvt_pk_bf16(float lo, float hi) {
    unsigned int r;
    asm("v_cvt_pk_bf16_f32 %0, %1, %2" : "=v"(r) : "v"(lo), "v"(hi));
    return r;
}

#if __has_builtin(__builtin_amdgcn_exp2f)
#define EX2(x) __builtin_amdgcn_exp2f(x)
#else
#define EX2(x) exp2f(x)
#endif

// ---------------- elementwise f32 -> bf16 ----------------
__global__ void cvt_k(const float* __restrict__ in, ushort* __restrict__ out, long n) {
    long stride = (long)gridDim.x * blockDim.x * 4;
    for (long i = ((long)blockIdx.x * blockDim.x + threadIdx.x) * 4; i < n; i += stride) {
        float4 f = *(const float4*)(in + i);
        *(ushort4*)(out + i) = make_ushort4(f2b(f.x), f2b(f.y), f2b(f.z), f2b(f.w));
    }
}

// ---------------- transpose + convert: out[c][r] = in[r][c] ----------------
__global__ void transpose_cvt_k(const float* __restrict__ in, ushort* __restrict__ outp,
                                int R, int C) {
    __shared__ float tile[64][65];
    int c0 = blockIdx.x * 64, r0 = blockIdx.y * 64;
    int tx = threadIdx.x & 63, ty = threadIdx.x >> 6;
#pragma unroll
    for (int p = 0; p < 16; ++p)
        tile[ty + p * 4][tx] = in[(long)(r0 + ty + p * 4) * C + c0 + tx];
    __syncthreads();
#pragma unroll
    for (int p = 0; p < 16; ++p)
        outp[(long)(c0 + ty + p * 4) * R + r0 + tx] = f2b(tile[tx][ty + p * 4]);
}

// ---------------- kv_cache -> c_kv out (f32) + bf16 copy ----------------
__global__ void kvcopy_k(const float* __restrict__ kv, float* __restrict__ cko,
                         ushort* __restrict__ ckb, int PAST, int T) {
    long n = (long)BB * PAST * LL;
    long pl2 = (long)PAST * LL;
    long stride = (long)gridDim.x * blockDim.x * 4;
    for (long i = ((long)blockIdx.x * blockDim.x + threadIdx.x) * 4; i < n; i += stride) {
        float4 f = *(const float4*)(kv + i);
        long b = i / pl2, wloc = i - b * pl2;
        long o = b * (long)T * LL + wloc;
        *(float4*)(cko + o) = f;
        *(ushort4*)(ckb + o) = make_ushort4(f2b(f.x), f2b(f.y), f2b(f.z), f2b(f.w));
    }
}

// ---------------- LayerNorm over L=512, one wave per row ----------------
__global__ __launch_bounds__(256) void ln_k(const float* __restrict__ cpre,
                                            const float* __restrict__ g, const float* __restrict__ be,
                                            float* __restrict__ cko, ushort* __restrict__ ckb,
                                            int S, int PAST, int T) {
    int wid = threadIdx.x >> 6, lane = threadIdx.x & 63;
    int row = blockIdx.x * 4 + wid;
    int b = row / S, s = row - b * S;
    const float* xr = cpre + (long)row * LL + lane * 8;
    float4 v0 = *(const float4*)xr;
    float4 v1 = *(const float4*)(xr + 4);
    float sum = v0.x + v0.y + v0.z + v0.w + v1.x + v1.y + v1.z + v1.w;
    float sq = v0.x * v0.x + v0.y * v0.y + v0.z * v0.z + v0.w * v0.w +
               v1.x * v1.x + v1.y * v1.y + v1.z * v1.z + v1.w * v1.w;
#pragma unroll
    for (int m = 1; m < 64; m <<= 1) { sum += __shfl_xor(sum, m, 64); sq += __shfl_xor(sq, m, 64); }
    float mu = sum * (1.0f / LL);
    float var = sq * (1.0f / LL) - mu * mu;
    float rstd = rsqrtf(var + 1e-5f);
    const float* gp = g + lane * 8;
    const float* bp = be + lane * 8;
    float4 g0 = *(const float4*)gp, g1 = *(const float4*)(gp + 4);
    float4 b0 = *(const float4*)bp, b1 = *(const float4*)(bp + 4);
    float y0 = (v0.x - mu) * rstd * g0.x + b0.x;
    float y1 = (v0.y - mu) * rstd * g0.y + b0.y;
    float y2 = (v0.z - mu) * rstd * g0.z + b0.z;
    float y3 = (v0.w - mu) * rstd * g0.w + b0.w;
    float y4 = (v1.x - mu) * rstd * g1.x + b1.x;
    float y5 = (v1.y - mu) * rstd * g1.y + b1.y;
    float y6 = (v1.z - mu) * rstd * g1.z + b1.z;
    float y7 = (v1.w - mu) * rstd * g1.w + b1.w;
    long o = ((long)b * T + PAST + s) * LL + lane * 8;
    *(float4*)(cko + o) = make_float4(y0, y1, y2, y3);
    *(float4*)(cko + o + 4) = make_float4(y4, y5, y6, y7);
    *(ushort4*)(ckb + o) = make_ushort4(f2b(y0), f2b(y1), f2b(y2), f2b(y3));
    *(ushort4*)(ckb + o + 4) = make_ushort4(f2b(y4), f2b(y5), f2b(y6), f2b(y7));
}

// ---------------- generic NT GEMM v3 (m97 single-buffer gll16) --------------
// global_load_lds width-16 into ONE [128][64] tile per operand (32 KB LDS ->
// 4 blocks/CU); XOR-swizzled source col + swizzled ds_read_b128 (r16-verified
// pair); 2 barriers per K-step (m97 structure: multi-block overlap hides the
// vmcnt(0) drain).
#define GEMM_RD_BAR()                                               \
    do {                                                            \
        asm volatile("s_waitcnt lgkmcnt(0)" ::: "memory");          \
        __builtin_amdgcn_s_barrier();                               \
    } while (0)
#define GEMM_VM_BAR()                                               \
    do {                                                            \
        asm volatile("s_waitcnt vmcnt(0) lgkmcnt(0)" ::: "memory"); \
        __builtin_amdgcn_s_barrier();                               \
    } while (0)

template <bool OUT_BF16>
__global__ __launch_bounds__(256) void gemm_nt(const ushort* __restrict__ A,
                                               const ushort* __restrict__ B,
                                               void* __restrict__ Cv,
                                               int K, int lda, int ldb, int ldc,
                                               long aHi, long aLo, long bHi, long bLo,
                                               long cHi, long cLo, int zdiv, float cscale) {
    __shared__ __align__(16) ushort Asm[8192];  // [m 128][k 64], 3-bit swizzled cols
    __shared__ __align__(16) ushort Bsm[8192];  // [n 128][k 64]
    const int tid = threadIdx.x, wid = tid >> 6, lane = tid & 63;
    const int z = blockIdx.z, zh = z / zdiv, zl = z % zdiv;
    A += zh * aHi + zl * aLo;
    B += zh * bHi + zl * bLo;
    const long cOff = zh * cHi + zl * cLo;
    const int m0 = blockIdx.x * 128, n0 = blockIdx.y * 128;
    const int wm = (wid >> 1) * 64, wn = (wid & 1) * 64;
    const int l15 = lane & 15;
    const int swr = (l15 & 7) << 3;           // read-side XOR (ushort units)
    const int vr = tid >> 3, vc = tid & 7;    // staging coords (32 rows x 8 cols/grp)
    const int scol = (vc ^ (vr & 7)) << 3;    // pre-swizzled source col (ushorts)
    f32x4 acc[4][4] = {};

    auto stageA = [&](int kt_) {
#pragma unroll
        for (int p = 0; p < 4; ++p)
            gll16(A + (long)(m0 + p * 32 + vr) * lda + kt_ + scol, &Asm[p * 2048 + tid * 8]);
    };
    auto stageB = [&](int kt_) {
#pragma unroll
        for (int p = 0; p < 4; ++p)
            gll16(B + (long)(n0 + p * 32 + vr) * ldb + kt_ + scol, &Bsm[p * 2048 + tid * 8]);
    };

    const int nkt = K >> 6;
    for (int ki = 0; ki < nkt; ++ki) {
        if (ki) GEMM_RD_BAR();        // previous tile's reads complete
        stageA(ki << 6);
        stageB(ki << 6);
        GEMM_VM_BAR();                // staged tile resident
        __builtin_amdgcn_s_setprio(1);
#pragma unroll
        for (int kk = 0; kk < 2; ++kk) {
            const int ko = kk * 32 + ((lane >> 4) << 3);
            bf16x8 af[4], bf[4];
#pragma unroll
            for (int i = 0; i < 4; ++i)
                af[i] = *(const bf16x8*)(&Asm[(wm + i * 16 + l15) * 64 + (ko ^ swr)]);
#pragma unroll
            for (int j = 0; j < 4; ++j)
                bf[j] = *(const bf16x8*)(&Bsm[(wn + j * 16 + l15) * 64 + (ko ^ swr)]);
#pragma unroll
            for (int i = 0; i < 4; ++i)
#pragma unroll
                for (int j = 0; j < 4; ++j)
                    acc[i][j] = __builtin_amdgcn_mfma_f32_16x16x32_bf16(af[i], bf[j], acc[i][j], 0, 0, 0);
        }
        __builtin_amdgcn_s_setprio(0);
    }
    const int cr = (lane >> 4) * 4, cc = l15;
#pragma unroll
    for (int i = 0; i < 4; ++i) {
#pragma unroll
        for (int r = 0; r < 4; ++r) {
            const long row = m0 + wm + i * 16 + cr + r;
#pragma unroll
            for (int j = 0; j < 4; ++j) {
                const long col = n0 + wn + j * 16 + cc;
                if (OUT_BF16)
                    ((ushort*)Cv)[cOff + row * ldc + col] = f2b(acc[i][j][r] * cscale);
                else
                    ((float*)Cv)[cOff + row * ldc + col] = acc[i][j][r] * cscale;
            }
        }
    }
}

// ---------------- flash attention (r17, unchanged) ---------------------------
#define PH_WAIT4()                                               \
    do {                                                         \
        asm volatile("s_waitcnt vmcnt(4) lgkmcnt(0)" ::: "memory"); \
        __builtin_amdgcn_s_barrier();                            \
    } while (0)
#define PH_WAIT0()                                               \
    do {                                                         \
        asm volatile("s_waitcnt vmcnt(0) lgkmcnt(0)" ::: "memory"); \
        __builtin_amdgcn_s_barrier();                            \
    } while (0)
#define RD_BAR()                                                 \
    do {                                                         \
        asm volatile("s_waitcnt lgkmcnt(0)" ::: "memory");       \
        __builtin_amdgcn_s_barrier();                            \
    } while (0)

__global__ __launch_bounds__(256, 4) void attn_k(const ushort* __restrict__ qbf,
                                                 const ushort* __restrict__ ktb,
                                                 const ushort* __restrict__ vtb,
                                                 ushort* __restrict__ ctxb,
                                                 int S, int T, int PAST) {
    __shared__ __align__(16) ushort bufK[64 * 128];   // [t][d], 4-bit XOR-swizzled cols
    __shared__ __align__(16) ushort bufV[128 * 64];   // [d][t], 3-bit XOR-swizzled cols
    __shared__ __align__(16) ushort pl[4][16][64];    // per-wave P [q][t], t XOR-swizzled
    const int tid = threadIdx.x, wid = tid >> 6, lane = tid & 63;
    // chunked XCD mapping + per-CU length balancing
    const int nsb = S >> 6;               // 32
    const int nwg = BB * HH * nsb;        // 1024
    const int cpx = nwg >> 3;             // 128
    const int id = (int)blockIdx.x;
    const int xcd = id & 7, k = id >> 3;
    const int r4 = k >> 5, c32 = k & 31;
    const int local = r4 * 32 + ((c32 + r4 * 8) & 31);
    const int orig = xcd * cpx + local;
    const int sblk = orig % nsb;
    const int h = (orig / nsb) % HH;
    const int b = orig / (nsb * HH);
    const int s0 = (nsb - 1 - sblk) * 64;  // longest-first within chunk

    const int g = lane >> 4, l15 = lane & 15, q8 = g << 3;
    const int swr = (l15 & 7) << 3;   // 3-bit read XOR (bufV / pl)
    const int swrK = l15 << 3;        // 4-bit read XOR (bufK)

    // Q fragments: per-head slice of x (scale*log2e folded into khat)
    bf16x8 qf[4];
    {
        const ushort* qb = qbf + ((long)b * S + s0 + wid * 16 + l15) * DV + h * DHD + q8;
#pragma unroll
        for (int kk = 0; kk < 4; ++kk) qf[kk] = *(const bf16x8*)(qb + kk * 32);
    }
    f32x4 cacc[8] = {};
    f32x4 sacc[4] = {};   // swapped: sacc[nf][r] = S[t = nf*16+g*4+r][q = l15] (log2 domain)
    float mrow = -1e30f, lrow = 0.f;  // per-lane, q = wid*16 + l15
    const int rl = tid >> 4, cc16 = tid & 15;
    const int vr = tid >> 3, vc = tid & 7;
    const int nfull = (s0 + PAST) / 64;
    const ushort* kbase = ktb + (long)b * T * DV + h * DHD;
    const ushort* vbase = vtb + ((long)b * DV + h * DHD) * T;
    const int kcol = (cc16 ^ rl) << 3;        // 4-bit pre-swizzled K source col
    const int vcol = (vc ^ (vr & 7)) << 3;    // 3-bit pre-swizzled V source col

    auto stageK = [&](int tt_) {
#pragma unroll
        for (int p = 0; p < 4; ++p)
            gll16(kbase + (long)(tt_ * 64 + p * 16 + rl) * DV + kcol, &bufK[p * 2048 + tid * 8]);
    };
    auto stageV = [&](int tt_) {
#pragma unroll
        for (int p = 0; p < 4; ++p)
            gll16(vbase + (long)(p * 32 + vr) * T + tt_ * 64 + vcol, &bufV[p * 2048 + tid * 8]);
    };

    stageK(0);
    stageV(0);

    for (int tt = 0; tt <= nfull; ++tt) {
        const bool last = (tt == nfull);
        // ---- phase A: wait K(tt); QK (swapped: out[t][q]) ----
        PH_WAIT4();
        __builtin_amdgcn_s_setprio(1);
#pragma unroll
        for (int kk = 0; kk < 4; ++kk) {
            const int ko = kk * 32 + q8;
#pragma unroll
            for (int nf = 0; nf < 4; ++nf) {
                bf16x8 af = *(const bf16x8*)(&bufK[(nf * 16 + l15) * 128 + (ko ^ swrK)]);
                sacc[nf] = __builtin_amdgcn_mfma_f32_16x16x32_bf16(af, qf[kk], sacc[nf], 0, 0, 0);
            }
        }
        __builtin_amdgcn_s_setprio(0);
        RD_BAR();                       // all waves done reading bufK
        if (!last) stageK(tt + 1);      // overwrite bufK with next K
        // ---- phase B: wait V(tt); softmax + PV ----
        if (last) { PH_WAIT0(); } else { PH_WAIT4(); }
        float pm = -1e30f;
#pragma unroll
        for (int nf = 0; nf < 4; ++nf)
#pragma unroll
            for (int r = 0; r < 4; ++r) {
                float v = sacc[nf][r];
                if (last) {
                    int tl = nf * 16 + (g << 2) + r;
                    int ql = wid * 16 + l15;
                    if (tl > ql) v = -1e30f;
                }
                sacc[nf][r] = v;
                pm = fmaxf(pm, v);
            }
        pm = fmaxf(pm, __shfl_xor(pm, 16, 64));
        pm = fmaxf(pm, __shfl_xor(pm, 32, 64));
        if (__any(pm > mrow + 11.5f)) {
            float mn = fmaxf(mrow, pm);
            float al = EX2(mrow - mn);
            mrow = mn;
            lrow *= al;
#pragma unroll
            for (int r = 0; r < 4; ++r) {
                float alr = __shfl(al, (g << 2) + r, 64);  // al for q-row g*4+r
#pragma unroll
                for (int df = 0; df < 8; ++df) cacc[df][r] *= alr;
            }
        }
        float ps = 0.f;
#pragma unroll
        for (int nf = 0; nf < 4; ++nf)
#pragma unroll
            for (int r = 0; r < 4; ++r) {
                float p = EX2(sacc[nf][r] - mrow);
                sacc[nf][r] = p;
                ps += p;
            }
        ps += __shfl_xor(ps, 16, 64);
        ps += __shfl_xor(ps, 32, 64);
        lrow += ps;
        // P -> wave-private swizzled LDS: packed pairs (t even; bit0 unaffected by swr)
#pragma unroll
        for (int nf = 0; nf < 4; ++nf)
#pragma unroll
            for (int rp = 0; rp < 2; ++rp) {
                unsigned int hb = cvt_pk_bf16(sacc[nf][rp * 2], sacc[nf][rp * 2 + 1]);
                const int tlo = nf * 16 + (g << 2) + rp * 2;
                *(unsigned int*)&pl[wid][l15][tlo ^ swr] = hb;
            }
#pragma unroll
        for (int nf = 0; nf < 4; ++nf) sacc[nf] = (f32x4){0.f, 0.f, 0.f, 0.f};
        // ctx += P * V
        __builtin_amdgcn_s_setprio(1);
#pragma unroll
        for (int kk = 0; kk < 2; ++kk) {
            bf16x8 a = *(const bf16x8*)(&pl[wid][l15][(kk * 32 + q8) ^ swr]);
#pragma unroll
            for (int df = 0; df < 8; ++df) {
                bf16x8 bv = *(const bf16x8*)(&bufV[(df * 16 + l15) * 64 + ((kk * 32 + q8) ^ swr)]);
                cacc[df] = __builtin_amdgcn_mfma_f32_16x16x32_bf16(a, bv, cacc[df], 0, 0, 0);
            }
        }
        __builtin_amdgcn_s_setprio(0);
        if (!last) {
            RD_BAR();                   // all waves done reading bufV
            stageV(tt + 1);
        }
    }
    // ---- epilogue ----
    const long rbase = (long)b * S + s0 + wid * 16 + (g << 2);
#pragma unroll
    for (int r = 0; r < 4; ++r) {
        float lr = __shfl(lrow, (g << 2) + r, 64);
        float inv = 1.0f / lr;
        const int d = h * DHD + l15;
#pragma unroll
        for (int df = 0; df < 8; ++df)
            ctxb[(rbase + r) * DV + d + df * 16] = f2b(cacc[df][r] * inv);
    }
}

extern "C" void kernel_launch(void* const* d_in, const int* in_sizes, int n_in,
                              void* d_out, int out_size, void* d_ws, size_t ws_size,
                              hipStream_t stream) {
    const float* x = (const float*)d_in[0];
    const float* kv = (const float*)d_in[1];
    const float* Wq = (const float*)d_in[2];
    const float* Wdkv = (const float*)d_in[3];
    const float* Wuk = (const float*)d_in[4];
    const float* Wuv = (const float*)d_in[5];
    const float* Wo = (const float*)d_in[6];
    const float* lng = (const float*)d_in[7];
    const float* lnbt = (const float*)d_in[8];
    const int S = in_sizes[0] / (BB * DV);     // 2048
    const int PAST = in_sizes[1] / (BB * LL);  // 2048
    const int T = S + PAST;                    // 4096

    float* out_p = (float*)d_out;                       // [B,S,D] f32
    float* ckv_out = out_p + (size_t)BB * S * DV;       // [B,T,L] f32

    char* w = (char*)d_ws;
    auto take = [&](size_t bytes) { char* p = w; w += (bytes + 255) & ~(size_t)255; return p; };
    ushort* xb    = (ushort*)take((size_t)BB * S * DV * 2);
    ushort* Wqb   = (ushort*)take((size_t)DV * DV * 2);
    ushort* WukT  = (ushort*)take((size_t)DV * LL * 2);   // [L][D] = Wuk^T
    ushort* Wdkvb = (ushort*)take((size_t)LL * DV * 2);
    ushort* Wuvb  = (ushort*)take((size_t)DV * LL * 2);
    ushort* Wob   = (ushort*)take((size_t)DV * DV * 2);
    ushort* absb  = (ushort*)take((size_t)DV * LL * 2);   // [D][L] = Wq@Wuk (scaled*log2e)
    float*  cpre  = (float*)take((size_t)BB * S * LL * 4);
    ushort* ckvb  = (ushort*)take((size_t)BB * T * LL * 2);
    ushort* vtb   = (ushort*)take((size_t)BB * DV * T * 2);  // [B][D][T]
    ushort* ktb   = (ushort*)take((size_t)BB * T * DV * 2);  // [B][T][D] khat
    ushort* ctxb  = (ushort*)take((size_t)BB * S * DV * 2);

    auto cvt = [&](const float* in, ushort* op, long n) {
        long nb = (n / 4 + 255) / 256;
        if (nb > 2048) nb = 2048;
        cvt_k<<<dim3((unsigned)nb), dim3(256), 0, stream>>>(in, op, n);
    };
    cvt(x, xb, (long)BB * S * DV);
    cvt(Wq, Wqb, (long)DV * DV);
    cvt(Wdkv, Wdkvb, (long)LL * DV);
    cvt(Wuv, Wuvb, (long)DV * LL);
    cvt(Wo, Wob, (long)DV * DV);
    transpose_cvt_k<<<dim3(LL / 64, DV / 64), dim3(256), 0, stream>>>(Wuk, WukT, DV, LL);
    kvcopy_k<<<dim3(2048), dim3(256), 0, stream>>>(kv, ckv_out, ckvb, PAST, T);

    // absorbed[j,l] = sum_i Wq[j,i]*Wuk[i,l], scaled by log2(e)/sqrt(dh) -> [D][L]
    gemm_nt<true><<<dim3(DV / 128, LL / 128, 1), dim3(256), 0, stream>>>(
        Wqb, WukT, absb, DV, DV, DV, LL, 0, 0, 0, 0, 0, 0, 1, 0.12751744900014818f);
    // c_pre = x * Wdkv^T  (f32)
    gemm_nt<false><<<dim3(BB * S / 128, LL / 128, 1), dim3(256), 0, stream>>>(
        xb, Wdkvb, cpre, DV, DV, DV, LL, 0, 0, 0, 0, 0, 0, 1, 1.0f);
    ln_k<<<dim3(BB * S / 4), dim3(256), 0, stream>>>(cpre, lng, lnbt, ckv_out, ckvb, S, PAST, T);
    // Vt[b] = Wuv * ckv[b]^T : [D][T] bf16
    gemm_nt<true><<<dim3(DV / 128, T / 128, BB), dim3(256), 0, stream>>>(
        Wuvb, ckvb, vtb, LL, LL, LL, T, 0, 0, (long)T * LL, 0, (long)DV * T, 0, 1, 1.0f);
    // khat[b] = ckv[b] @ absorbed^T : [T][D] bf16
    gemm_nt<true><<<dim3(T / 128, DV / 128, BB), dim3(256), 0, stream>>>(
        ckvb, absb, ktb, LL, LL, LL, DV, (long)T * LL, 0, 0, 0, (long)T * DV, 0, 1, 1.0f);
    // attention (d=128 MHA; Q = per-head slice of x)
    attn_k<<<dim3(BB * HH * (S / 64)), dim3(256), 0, stream>>>(xb, ktb, vtb, ctxb, S, T, PAST);
    // out = ctx * Wo^T (f32)
    gemm_nt<false><<<dim3(BB * S / 128, DV / 128, 1), dim3(256), 0, stream>>>(
        ctxb, Wob, out_p, DV, DV, DV, DV, 0, 0, 0, 0, 0, 0, 1, 1.0f);
}

// Round 20
// 317.333 us; speedup vs baseline: 1.5964x; 1.0917x over previous
//
#include <hip/hip_runtime.h>
#include <cstdint>

#define DV 2048
#define HH 16
#define DHD 128
#define LL 512
#define BB 2

typedef __attribute__((ext_vector_type(8))) short bf16x8;
typedef __attribute__((ext_vector_type(4))) float f32x4;
typedef __attribute__((ext_vector_type(4))) int i32x4;

typedef __attribute__((address_space(1))) const void* gas_cp;
typedef __attribute__((address_space(3))) void* las_p;

__device__ __forceinline__ void gll16(const void* g, void* l) {
    __builtin_amdgcn_global_load_lds((gas_cp)g, (las_p)l, 16, 0, 0);
}

__device__ __forceinline__ unsigned short f2b(float f) {
    union { float f; unsigned int u; } v; v.f = f;
    unsigned int u = v.u;
    return (unsigned short)((u + 0x7FFFu + ((u >> 16) & 1u)) >> 16);
}

// pack two f32 -> 2xbf16 in one u32 (v_cvt_pk_bf16_f32; no builtin on gfx950)
__device__ __forceinline__ unsigned int cvt_pk_bf16(float lo, float hi) {
    unsigned int r;
    asm("v_cvt_pk_bf16_f32 %0, %1, %2" : "=v"(r) : "v"(lo), "v"(hi));
    return r;
}

#if __has_builtin(__builtin_amdgcn_exp2f)
#define EX2(x) __builtin_amdgcn_exp2f(x)
#else
#define EX2(x) exp2f(x)
#endif

// ---------------- elementwise f32 -> bf16 ----------------
__global__ void cvt_k(const float* __restrict__ in, ushort* __restrict__ out, long n) {
    long stride = (long)gridDim.x * blockDim.x * 4;
    for (long i = ((long)blockIdx.x * blockDim.x + threadIdx.x) * 4; i < n; i += stride) {
        float4 f = *(const float4*)(in + i);
        *(ushort4*)(out + i) = make_ushort4(f2b(f.x), f2b(f.y), f2b(f.z), f2b(f.w));
    }
}

// ---------------- transpose + convert: out[c][r] = in[r][c] ----------------
__global__ void transpose_cvt_k(const float* __restrict__ in, ushort* __restrict__ outp,
                                int R, int C) {
    __shared__ float tile[64][65];
    int c0 = blockIdx.x * 64, r0 = blockIdx.y * 64;
    int tx = threadIdx.x & 63, ty = threadIdx.x >> 6;
#pragma unroll
    for (int p = 0; p < 16; ++p)
        tile[ty + p * 4][tx] = in[(long)(r0 + ty + p * 4) * C + c0 + tx];
    __syncthreads();
#pragma unroll
    for (int p = 0; p < 16; ++p)
        outp[(long)(c0 + ty + p * 4) * R + r0 + tx] = f2b(tile[tx][ty + p * 4]);
}

// ---------------- kv_cache -> c_kv out (f32) + bf16 copy ----------------
__global__ void kvcopy_k(const float* __restrict__ kv, float* __restrict__ cko,
                         ushort* __restrict__ ckb, int PAST, int T) {
    long n = (long)BB * PAST * LL;
    long pl2 = (long)PAST * LL;
    long stride = (long)gridDim.x * blockDim.x * 4;
    for (long i = ((long)blockIdx.x * blockDim.x + threadIdx.x) * 4; i < n; i += stride) {
        float4 f = *(const float4*)(kv + i);
        long b = i / pl2, wloc = i - b * pl2;
        long o = b * (long)T * LL + wloc;
        *(float4*)(cko + o) = f;
        *(ushort4*)(ckb + o) = make_ushort4(f2b(f.x), f2b(f.y), f2b(f.z), f2b(f.w));
    }
}

// ---------------- LayerNorm over L=512, one wave per row ----------------
__global__ __launch_bounds__(256) void ln_k(const float* __restrict__ cpre,
                                            const float* __restrict__ g, const float* __restrict__ be,
                                            float* __restrict__ cko, ushort* __restrict__ ckb,
                                            int S, int PAST, int T) {
    int wid = threadIdx.x >> 6, lane = threadIdx.x & 63;
    int row = blockIdx.x * 4 + wid;
    int b = row / S, s = row - b * S;
    const float* xr = cpre + (long)row * LL + lane * 8;
    float4 v0 = *(const float4*)xr;
    float4 v1 = *(const float4*)(xr + 4);
    float sum = v0.x + v0.y + v0.z + v0.w + v1.x + v1.y + v1.z + v1.w;
    float sq = v0.x * v0.x + v0.y * v0.y + v0.z * v0.z + v0.w * v0.w +
               v1.x * v1.x + v1.y * v1.y + v1.z * v1.z + v1.w * v1.w;
#pragma unroll
    for (int m = 1; m < 64; m <<= 1) { sum += __shfl_xor(sum, m, 64); sq += __shfl_xor(sq, m, 64); }
    float mu = sum * (1.0f / LL);
    float var = sq * (1.0f / LL) - mu * mu;
    float rstd = rsqrtf(var + 1e-5f);
    const float* gp = g + lane * 8;
    const float* bp = be + lane * 8;
    float4 g0 = *(const float4*)gp, g1 = *(const float4*)(gp + 4);
    float4 b0 = *(const float4*)bp, b1 = *(const float4*)(bp + 4);
    float y0 = (v0.x - mu) * rstd * g0.x + b0.x;
    float y1 = (v0.y - mu) * rstd * g0.y + b0.y;
    float y2 = (v0.z - mu) * rstd * g0.z + b0.z;
    float y3 = (v0.w - mu) * rstd * g0.w + b0.w;
    float y4 = (v1.x - mu) * rstd * g1.x + b1.x;
    float y5 = (v1.y - mu) * rstd * g1.y + b1.y;
    float y6 = (v1.z - mu) * rstd * g1.z + b1.z;
    float y7 = (v1.w - mu) * rstd * g1.w + b1.w;
    long o = ((long)b * T + PAST + s) * LL + lane * 8;
    *(float4*)(cko + o) = make_float4(y0, y1, y2, y3);
    *(float4*)(cko + o + 4) = make_float4(y4, y5, y6, y7);
    *(ushort4*)(ckb + o) = make_ushort4(f2b(y0), f2b(y1), f2b(y2), f2b(y3));
    *(ushort4*)(ckb + o + 4) = make_ushort4(f2b(y4), f2b(y5), f2b(y6), f2b(y7));
}

// ---------------- generic NT GEMM (r15 version): C = cscale * A * B^T -------
template <bool OUT_BF16>
__global__ __launch_bounds__(256, 2) void gemm_nt(const ushort* __restrict__ A,
                                                  const ushort* __restrict__ B,
                                                  void* __restrict__ Cv,
                                                  int K, int lda, int ldb, int ldc,
                                                  long aHi, long aLo, long bHi, long bLo,
                                                  long cHi, long cLo, int zdiv, float cscale) {
    __shared__ __align__(16) ushort Asm[128 * 72];
    __shared__ __align__(16) ushort Bsm[128 * 72];
    const int tid = threadIdx.x, wid = tid >> 6, lane = tid & 63;
    const int z = blockIdx.z, zh = z / zdiv, zl = z % zdiv;
    A += zh * aHi + zl * aLo;
    B += zh * bHi + zl * bLo;
    const long cOff = zh * cHi + zl * cLo;
    const int m0 = blockIdx.x * 128, n0 = blockIdx.y * 128;
    const int wm = (wid >> 1) * 64, wn = (wid & 1) * 64;
    f32x4 acc[4][4] = {};
    const int l8 = lane & 7;
    const int rowA = wid * 8 + (lane >> 3);
    const ushort* Ag = A + (long)(m0 + rowA) * lda + l8 * 8;
    const ushort* Bg = B + (long)(n0 + rowA) * ldb + l8 * 8;

    i32x4 ra[4], rb[4];
#pragma unroll
    for (int p = 0; p < 4; ++p) {
        ra[p] = *(const i32x4*)(Ag + (long)p * 32 * lda);
        rb[p] = *(const i32x4*)(Bg + (long)p * 32 * ldb);
    }
    for (int kt = 0; kt < K; kt += 64) {
        __syncthreads();
#pragma unroll
        for (int p = 0; p < 4; ++p) {
            *(i32x4*)(Asm + (p * 32 + rowA) * 72 + l8 * 8) = ra[p];
            *(i32x4*)(Bsm + (p * 32 + rowA) * 72 + l8 * 8) = rb[p];
        }
        __syncthreads();
        if (kt + 64 < K) {
#pragma unroll
            for (int p = 0; p < 4; ++p) {
                ra[p] = *(const i32x4*)(Ag + (long)p * 32 * lda + kt + 64);
                rb[p] = *(const i32x4*)(Bg + (long)p * 32 * ldb + kt + 64);
            }
        }
#pragma unroll
        for (int kk = 0; kk < 2; ++kk) {
            const int ko = kk * 32 + ((lane >> 4) << 3);
            bf16x8 af[4], bf[4];
#pragma unroll
            for (int i = 0; i < 4; ++i)
                af[i] = *(const bf16x8*)(Asm + (wm + i * 16 + (lane & 15)) * 72 + ko);
#pragma unroll
            for (int j = 0; j < 4; ++j)
                bf[j] = *(const bf16x8*)(Bsm + (wn + j * 16 + (lane & 15)) * 72 + ko);
#pragma unroll
            for (int i = 0; i < 4; ++i)
#pragma unroll
                for (int j = 0; j < 4; ++j)
                    acc[i][j] = __builtin_amdgcn_mfma_f32_16x16x32_bf16(af[i], bf[j], acc[i][j], 0, 0, 0);
        }
        __syncthreads();
    }
    const int cr = (lane >> 4) * 4, cc = lane & 15;
#pragma unroll
    for (int i = 0; i < 4; ++i) {
#pragma unroll
        for (int r = 0; r < 4; ++r) {
            const long row = m0 + wm + i * 16 + cr + r;
#pragma unroll
            for (int j = 0; j < 4; ++j) {
                const long col = n0 + wn + j * 16 + cc;
                if (OUT_BF16)
                    ((ushort*)Cv)[cOff + row * ldc + col] = f2b(acc[i][j][r] * cscale);
                else
                    ((float*)Cv)[cOff + row * ldc + col] = acc[i][j][r] * cscale;
            }
        }
    }
}

// ---------------- fused pair GEMM: absb (bf16 out) + cpre (f32 out) ----------
// Both problems share K=2048, lda=ldb=DV, ldc=LL, N=512. blockIdx.x<16 -> absb
// (M=2048); else -> cpre (M=4096). One launch, 192 blocks instead of two
// serialized launches of 64 and 128 blocks.
__global__ __launch_bounds__(256, 2) void gemm_pair_k(const ushort* __restrict__ A0,
                                                      const ushort* __restrict__ B0,
                                                      ushort* __restrict__ C0,
                                                      const ushort* __restrict__ A1,
                                                      const ushort* __restrict__ B1,
                                                      float* __restrict__ C1,
                                                      float cs0) {
    __shared__ __align__(16) ushort Asm[128 * 72];
    __shared__ __align__(16) ushort Bsm[128 * 72];
    const int tid = threadIdx.x, wid = tid >> 6, lane = tid & 63;
    const int bx = (int)blockIdx.x;
    const bool p0 = (bx < 16);
    const ushort* A = p0 ? A0 : A1;
    const ushort* B = p0 ? B0 : B1;
    const int m0 = (p0 ? bx : bx - 16) * 128;
    const int n0 = blockIdx.y * 128;
    const float cs = p0 ? cs0 : 1.0f;
    f32x4 acc[4][4] = {};
    const int l8 = lane & 7;
    const int rowA = wid * 8 + (lane >> 3);
    const ushort* Ag = A + (long)(m0 + rowA) * DV + l8 * 8;
    const ushort* Bg = B + (long)(n0 + rowA) * DV + l8 * 8;

    i32x4 ra[4], rb[4];
#pragma unroll
    for (int p = 0; p < 4; ++p) {
        ra[p] = *(const i32x4*)(Ag + (long)p * 32 * DV);
        rb[p] = *(const i32x4*)(Bg + (long)p * 32 * DV);
    }
    for (int kt = 0; kt < DV; kt += 64) {
        __syncthreads();
#pragma unroll
        for (int p = 0; p < 4; ++p) {
            *(i32x4*)(Asm + (p * 32 + rowA) * 72 + l8 * 8) = ra[p];
            *(i32x4*)(Bsm + (p * 32 + rowA) * 72 + l8 * 8) = rb[p];
        }
        __syncthreads();
        if (kt + 64 < DV) {
#pragma unroll
            for (int p = 0; p < 4; ++p) {
                ra[p] = *(const i32x4*)(Ag + (long)p * 32 * DV + kt + 64);
                rb[p] = *(const i32x4*)(Bg + (long)p * 32 * DV + kt + 64);
            }
        }
#pragma unroll
        for (int kk = 0; kk < 2; ++kk) {
            const int ko = kk * 32 + ((lane >> 4) << 3);
            bf16x8 af[4], bf[4];
#pragma unroll
            for (int i = 0; i < 4; ++i)
                af[i] = *(const bf16x8*)(Asm + ((wid >> 1) * 64 + i * 16 + (lane & 15)) * 72 + ko);
#pragma unroll
            for (int j = 0; j < 4; ++j)
                bf[j] = *(const bf16x8*)(Bsm + ((wid & 1) * 64 + j * 16 + (lane & 15)) * 72 + ko);
#pragma unroll
            for (int i = 0; i < 4; ++i)
#pragma unroll
                for (int j = 0; j < 4; ++j)
                    acc[i][j] = __builtin_amdgcn_mfma_f32_16x16x32_bf16(af[i], bf[j], acc[i][j], 0, 0, 0);
        }
        __syncthreads();
    }
    const int wm = (wid >> 1) * 64, wn = (wid & 1) * 64;
    const int cr = (lane >> 4) * 4, cc = lane & 15;
#pragma unroll
    for (int i = 0; i < 4; ++i) {
#pragma unroll
        for (int r = 0; r < 4; ++r) {
            const long row = m0 + wm + i * 16 + cr + r;
#pragma unroll
            for (int j = 0; j < 4; ++j) {
                const long col = n0 + wn + j * 16 + cc;
                if (p0)
                    C0[row * LL + col] = f2b(acc[i][j][r] * cs);
                else
                    C1[row * LL + col] = acc[i][j][r];
            }
        }
    }
}

// ---------------- flash attention (r17, unchanged) ---------------------------
#define PH_WAIT4()                                               \
    do {                                                         \
        asm volatile("s_waitcnt vmcnt(4) lgkmcnt(0)" ::: "memory"); \
        __builtin_amdgcn_s_barrier();                            \
    } while (0)
#define PH_WAIT0()                                               \
    do {                                                         \
        asm volatile("s_waitcnt vmcnt(0) lgkmcnt(0)" ::: "memory"); \
        __builtin_amdgcn_s_barrier();                            \
    } while (0)
#define RD_BAR()                                                 \
    do {                                                         \
        asm volatile("s_waitcnt lgkmcnt(0)" ::: "memory");       \
        __builtin_amdgcn_s_barrier();                            \
    } while (0)

__global__ __launch_bounds__(256, 4) void attn_k(const ushort* __restrict__ qbf,
                                                 const ushort* __restrict__ ktb,
                                                 const ushort* __restrict__ vtb,
                                                 ushort* __restrict__ ctxb,
                                                 int S, int T, int PAST) {
    __shared__ __align__(16) ushort bufK[64 * 128];   // [t][d], 4-bit XOR-swizzled cols
    __shared__ __align__(16) ushort bufV[128 * 64];   // [d][t], 3-bit XOR-swizzled cols
    __shared__ __align__(16) ushort pl[4][16][64];    // per-wave P [q][t], t XOR-swizzled
    const int tid = threadIdx.x, wid = tid >> 6, lane = tid & 63;
    // chunked XCD mapping + per-CU length balancing
    const int nsb = S >> 6;               // 32
    const int nwg = BB * HH * nsb;        // 1024
    const int cpx = nwg >> 3;             // 128
    const int id = (int)blockIdx.x;
    const int xcd = id & 7, k = id >> 3;
    const int r4 = k >> 5, c32 = k & 31;
    const int local = r4 * 32 + ((c32 + r4 * 8) & 31);
    const int orig = xcd * cpx + local;
    const int sblk = orig % nsb;
    const int h = (orig / nsb) % HH;
    const int b = orig / (nsb * HH);
    const int s0 = (nsb - 1 - sblk) * 64;  // longest-first within chunk

    const int g = lane >> 4, l15 = lane & 15, q8 = g << 3;
    const int swr = (l15 & 7) << 3;   // 3-bit read XOR (bufV / pl)
    const int swrK = l15 << 3;        // 4-bit read XOR (bufK)

    // Q fragments: per-head slice of x (scale*log2e folded into khat)
    bf16x8 qf[4];
    {
        const ushort* qb = qbf + ((long)b * S + s0 + wid * 16 + l15) * DV + h * DHD + q8;
#pragma unroll
        for (int kk = 0; kk < 4; ++kk) qf[kk] = *(const bf16x8*)(qb + kk * 32);
    }
    f32x4 cacc[8] = {};
    f32x4 sacc[4] = {};   // swapped: sacc[nf][r] = S[t = nf*16+g*4+r][q = l15] (log2 domain)
    float mrow = -1e30f, lrow = 0.f;  // per-lane, q = wid*16 + l15
    const int rl = tid >> 4, cc16 = tid & 15;
    const int vr = tid >> 3, vc = tid & 7;
    const int nfull = (s0 + PAST) / 64;
    const ushort* kbase = ktb + (long)b * T * DV + h * DHD;
    const ushort* vbase = vtb + ((long)b * DV + h * DHD) * T;
    const int kcol = (cc16 ^ rl) << 3;        // 4-bit pre-swizzled K source col
    const int vcol = (vc ^ (vr & 7)) << 3;    // 3-bit pre-swizzled V source col

    auto stageK = [&](int tt_) {
#pragma unroll
        for (int p = 0; p < 4; ++p)
            gll16(kbase + (long)(tt_ * 64 + p * 16 + rl) * DV + kcol, &bufK[p * 2048 + tid * 8]);
    };
    auto stageV = [&](int tt_) {
#pragma unroll
        for (int p = 0; p < 4; ++p)
            gll16(vbase + (long)(p * 32 + vr) * T + tt_ * 64 + vcol, &bufV[p * 2048 + tid * 8]);
    };

    stageK(0);
    stageV(0);

    for (int tt = 0; tt <= nfull; ++tt) {
        const bool last = (tt == nfull);
        // ---- phase A: wait K(tt); QK (swapped: out[t][q]) ----
        PH_WAIT4();
        __builtin_amdgcn_s_setprio(1);
#pragma unroll
        for (int kk = 0; kk < 4; ++kk) {
            const int ko = kk * 32 + q8;
#pragma unroll
            for (int nf = 0; nf < 4; ++nf) {
                bf16x8 af = *(const bf16x8*)(&bufK[(nf * 16 + l15) * 128 + (ko ^ swrK)]);
                sacc[nf] = __builtin_amdgcn_mfma_f32_16x16x32_bf16(af, qf[kk], sacc[nf], 0, 0, 0);
            }
        }
        __builtin_amdgcn_s_setprio(0);
        RD_BAR();                       // all waves done reading bufK
        if (!last) stageK(tt + 1);      // overwrite bufK with next K
        // ---- phase B: wait V(tt); softmax + PV ----
        if (last) { PH_WAIT0(); } else { PH_WAIT4(); }
        float pm = -1e30f;
#pragma unroll
        for (int nf = 0; nf < 4; ++nf)
#pragma unroll
            for (int r = 0; r < 4; ++r) {
                float v = sacc[nf][r];
                if (last) {
                    int tl = nf * 16 + (g << 2) + r;
                    int ql = wid * 16 + l15;
                    if (tl > ql) v = -1e30f;
                }
                sacc[nf][r] = v;
                pm = fmaxf(pm, v);
            }
        pm = fmaxf(pm, __shfl_xor(pm, 16, 64));
        pm = fmaxf(pm, __shfl_xor(pm, 32, 64));
        if (__any(pm > mrow + 11.5f)) {
            float mn = fmaxf(mrow, pm);
            float al = EX2(mrow - mn);
            mrow = mn;
            lrow *= al;
#pragma unroll
            for (int r = 0; r < 4; ++r) {
                float alr = __shfl(al, (g << 2) + r, 64);  // al for q-row g*4+r
#pragma unroll
                for (int df = 0; df < 8; ++df) cacc[df][r] *= alr;
            }
        }
        float ps = 0.f;
#pragma unroll
        for (int nf = 0; nf < 4; ++nf)
#pragma unroll
            for (int r = 0; r < 4; ++r) {
                float p = EX2(sacc[nf][r] - mrow);
                sacc[nf][r] = p;
                ps += p;
            }
        ps += __shfl_xor(ps, 16, 64);
        ps += __shfl_xor(ps, 32, 64);
        lrow += ps;
        // P -> wave-private swizzled LDS: packed pairs (t even; bit0 unaffected by swr)
#pragma unroll
        for (int nf = 0; nf < 4; ++nf)
#pragma unroll
            for (int rp = 0; rp < 2; ++rp) {
                unsigned int hb = cvt_pk_bf16(sacc[nf][rp * 2], sacc[nf][rp * 2 + 1]);
                const int tlo = nf * 16 + (g << 2) + rp * 2;
                *(unsigned int*)&pl[wid][l15][tlo ^ swr] = hb;
            }
#pragma unroll
        for (int nf = 0; nf < 4; ++nf) sacc[nf] = (f32x4){0.f, 0.f, 0.f, 0.f};
        // ctx += P * V
        __builtin_amdgcn_s_setprio(1);
#pragma unroll
        for (int kk = 0; kk < 2; ++kk) {
            bf16x8 a = *(const bf16x8*)(&pl[wid][l15][(kk * 32 + q8) ^ swr]);
#pragma unroll
            for (int df = 0; df < 8; ++df) {
                bf16x8 bv = *(const bf16x8*)(&bufV[(df * 16 + l15) * 64 + ((kk * 32 + q8) ^ swr)]);
                cacc[df] = __builtin_amdgcn_mfma_f32_16x16x32_bf16(a, bv, cacc[df], 0, 0, 0);
            }
        }
        __builtin_amdgcn_s_setprio(0);
        if (!last) {
            RD_BAR();                   // all waves done reading bufV
            stageV(tt + 1);
        }
    }
    // ---- epilogue ----
    const long rbase = (long)b * S + s0 + wid * 16 + (g << 2);
#pragma unroll
    for (int r = 0; r < 4; ++r) {
        float lr = __shfl(lrow, (g << 2) + r, 64);
        float inv = 1.0f / lr;
        const int d = h * DHD + l15;
#pragma unroll
        for (int df = 0; df < 8; ++df)
            ctxb[(rbase + r) * DV + d + df * 16] = f2b(cacc[df][r] * inv);
    }
}

extern "C" void kernel_launch(void* const* d_in, const int* in_sizes, int n_in,
                              void* d_out, int out_size, void* d_ws, size_t ws_size,
                              hipStream_t stream) {
    const float* x = (const float*)d_in[0];
    const float* kv = (const float*)d_in[1];
    const float* Wq = (const float*)d_in[2];
    const float* Wdkv = (const float*)d_in[3];
    const float* Wuk = (const float*)d_in[4];
    const float* Wuv = (const float*)d_in[5];
    const float* Wo = (const float*)d_in[6];
    const float* lng = (const float*)d_in[7];
    const float* lnbt = (const float*)d_in[8];
    const int S = in_sizes[0] / (BB * DV);     // 2048
    const int PAST = in_sizes[1] / (BB * LL);  // 2048
    const int T = S + PAST;                    // 4096

    float* out_p = (float*)d_out;                       // [B,S,D] f32
    float* ckv_out = out_p + (size_t)BB * S * DV;       // [B,T,L] f32

    char* w = (char*)d_ws;
    auto take = [&](size_t bytes) { char* p = w; w += (bytes + 255) & ~(size_t)255; return p; };
    ushort* xb    = (ushort*)take((size_t)BB * S * DV * 2);
    ushort* Wqb   = (ushort*)take((size_t)DV * DV * 2);
    ushort* WukT  = (ushort*)take((size_t)DV * LL * 2);   // [L][D] = Wuk^T
    ushort* Wdkvb = (ushort*)take((size_t)LL * DV * 2);
    ushort* Wuvb  = (ushort*)take((size_t)DV * LL * 2);
    ushort* Wob   = (ushort*)take((size_t)DV * DV * 2);
    ushort* absb  = (ushort*)take((size_t)DV * LL * 2);   // [D][L] = Wq@Wuk (scaled*log2e)
    float*  cpre  = (float*)take((size_t)BB * S * LL * 4);
    ushort* ckvb  = (ushort*)take((size_t)BB * T * LL * 2);
    ushort* vtb   = (ushort*)take((size_t)BB * DV * T * 2);  // [B][D][T]
    ushort* ktb   = (ushort*)take((size_t)BB * T * DV * 2);  // [B][T][D] khat
    ushort* ctxb  = (ushort*)take((size_t)BB * S * DV * 2);

    auto cvt = [&](const float* in, ushort* op, long n) {
        long nb = (n / 4 + 255) / 256;
        if (nb > 2048) nb = 2048;
        cvt_k<<<dim3((unsigned)nb), dim3(256), 0, stream>>>(in, op, n);
    };
    cvt(x, xb, (long)BB * S * DV);
    cvt(Wq, Wqb, (long)DV * DV);
    cvt(Wdkv, Wdkvb, (long)LL * DV);
    cvt(Wuv, Wuvb, (long)DV * LL);
    cvt(Wo, Wob, (long)DV * DV);
    transpose_cvt_k<<<dim3(LL / 64, DV / 64), dim3(256), 0, stream>>>(Wuk, WukT, DV, LL);
    kvcopy_k<<<dim3(2048), dim3(256), 0, stream>>>(kv, ckv_out, ckvb, PAST, T);

    // fused: absb = log2e/sqrt(dh) * Wq @ Wuk   AND   cpre = x @ Wdkv^T (f32)
    gemm_pair_k<<<dim3(48, LL / 128), dim3(256), 0, stream>>>(
        Wqb, WukT, absb, xb, Wdkvb, cpre, 0.12751744900014818f);
    ln_k<<<dim3(BB * S / 4), dim3(256), 0, stream>>>(cpre, lng, lnbt, ckv_out, ckvb, S, PAST, T);
    // Vt[b] = Wuv * ckv[b]^T : [D][T] bf16
    gemm_nt<true><<<dim3(DV / 128, T / 128, BB), dim3(256), 0, stream>>>(
        Wuvb, ckvb, vtb, LL, LL, LL, T, 0, 0, (long)T * LL, 0, (long)DV * T, 0, 1, 1.0f);
    // khat[b] = ckv[b] @ absorbed^T : [T][D] bf16
    gemm_nt<true><<<dim3(T / 128, DV / 128, BB), dim3(256), 0, stream>>>(
        ckvb, absb, ktb, LL, LL, LL, DV, (long)T * LL, 0, 0, 0, (long)T * DV, 0, 1, 1.0f);
    // attention (d=128 MHA; Q = per-head slice of x)
    attn_k<<<dim3(BB * HH * (S / 64)), dim3(256), 0, stream>>>(xb, ktb, vtb, ctxb, S, T, PAST);
    // out = ctx * Wo^T (f32)
    gemm_nt<false><<<dim3(BB * S / 128, DV / 128, 1), dim3(256), 0, stream>>>(
        ctxb, Wob, out_p, DV, DV, DV, DV, 0, 0, 0, 0, 0, 0, 1, 1.0f);
}

// Round 21
// 307.402 us; speedup vs baseline: 1.6480x; 1.0323x over previous
//
#include <hip/hip_runtime.h>
#include <cstdint>

#define DV 2048
#define HH 16
#define DHD 128
#define LL 512
#define BB 2

typedef __attribute__((ext_vector_type(8))) short bf16x8;
typedef __attribute__((ext_vector_type(4))) float f32x4;
typedef __attribute__((ext_vector_type(4))) int i32x4;

typedef __attribute__((address_space(1))) const void* gas_cp;
typedef __attribute__((address_space(3))) void* las_p;

__device__ __forceinline__ void gll16(const void* g, void* l) {
    __builtin_amdgcn_global_load_lds((gas_cp)g, (las_p)l, 16, 0, 0);
}

__device__ __forceinline__ unsigned short f2b(float f) {
    union { float f; unsigned int u; } v; v.f = f;
    unsigned int u = v.u;
    return (unsigned short)((u + 0x7FFFu + ((u >> 16) & 1u)) >> 16);
}

// pack two f32 -> 2xbf16 in one u32 (v_cvt_pk_bf16_f32; no builtin on gfx950)
__device__ __forceinline__ unsigned int cvt_pk_bf16(float lo, float hi) {
    unsigned int r;
    asm("v_cvt_pk_bf16_f32 %0, %1, %2" : "=v"(r) : "v"(lo), "v"(hi));
    return r;
}

#if __has_builtin(__builtin_amdgcn_exp2f)
#define EX2(x) __builtin_amdgcn_exp2f(x)
#else
#define EX2(x) exp2f(x)
#endif

// ---------------- fused elementwise f32 -> bf16 over 5 buffers ----------------
__global__ void cvt5_k(const float* __restrict__ i0, ushort* __restrict__ o0, long n0,
                       const float* __restrict__ i1, ushort* __restrict__ o1, long n1,
                       const float* __restrict__ i2, ushort* __restrict__ o2, long n2,
                       const float* __restrict__ i3, ushort* __restrict__ o3, long n3,
                       const float* __restrict__ i4, ushort* __restrict__ o4, long n4) {
    const long c0 = n0, c1 = c0 + n1, c2 = c1 + n2, c3 = c2 + n3, c4 = c3 + n4;
    long stride = (long)gridDim.x * blockDim.x * 4;
    for (long i = ((long)blockIdx.x * blockDim.x + threadIdx.x) * 4; i < c4; i += stride) {
        const float* in;
        ushort* out;
        long off;
        if (i < c0)      { in = i0; out = o0; off = i; }
        else if (i < c1) { in = i1; out = o1; off = i - c0; }
        else if (i < c2) { in = i2; out = o2; off = i - c1; }
        else if (i < c3) { in = i3; out = o3; off = i - c2; }
        else             { in = i4; out = o4; off = i - c3; }
        float4 f = *(const float4*)(in + off);
        *(ushort4*)(out + off) = make_ushort4(f2b(f.x), f2b(f.y), f2b(f.z), f2b(f.w));
    }
}

// ---------------- transpose + convert: out[c][r] = in[r][c] ----------------
__global__ void transpose_cvt_k(const float* __restrict__ in, ushort* __restrict__ outp,
                                int R, int C) {
    __shared__ float tile[64][65];
    int c0 = blockIdx.x * 64, r0 = blockIdx.y * 64;
    int tx = threadIdx.x & 63, ty = threadIdx.x >> 6;
#pragma unroll
    for (int p = 0; p < 16; ++p)
        tile[ty + p * 4][tx] = in[(long)(r0 + ty + p * 4) * C + c0 + tx];
    __syncthreads();
#pragma unroll
    for (int p = 0; p < 16; ++p)
        outp[(long)(c0 + ty + p * 4) * R + r0 + tx] = f2b(tile[tx][ty + p * 4]);
}

// ---------------- kv_cache -> c_kv out (f32) + bf16 copy ----------------
__global__ void kvcopy_k(const float* __restrict__ kv, float* __restrict__ cko,
                         ushort* __restrict__ ckb, int PAST, int T) {
    long n = (long)BB * PAST * LL;
    long pl2 = (long)PAST * LL;
    long stride = (long)gridDim.x * blockDim.x * 4;
    for (long i = ((long)blockIdx.x * blockDim.x + threadIdx.x) * 4; i < n; i += stride) {
        float4 f = *(const float4*)(kv + i);
        long b = i / pl2, wloc = i - b * pl2;
        long o = b * (long)T * LL + wloc;
        *(float4*)(cko + o) = f;
        *(ushort4*)(ckb + o) = make_ushort4(f2b(f.x), f2b(f.y), f2b(f.z), f2b(f.w));
    }
}

// ---------------- LayerNorm over L=512, one wave per row ----------------
__global__ __launch_bounds__(256) void ln_k(const float* __restrict__ cpre,
                                            const float* __restrict__ g, const float* __restrict__ be,
                                            float* __restrict__ cko, ushort* __restrict__ ckb,
                                            int S, int PAST, int T) {
    int wid = threadIdx.x >> 6, lane = threadIdx.x & 63;
    int row = blockIdx.x * 4 + wid;
    int b = row / S, s = row - b * S;
    const float* xr = cpre + (long)row * LL + lane * 8;
    float4 v0 = *(const float4*)xr;
    float4 v1 = *(const float4*)(xr + 4);
    float sum = v0.x + v0.y + v0.z + v0.w + v1.x + v1.y + v1.z + v1.w;
    float sq = v0.x * v0.x + v0.y * v0.y + v0.z * v0.z + v0.w * v0.w +
               v1.x * v1.x + v1.y * v1.y + v1.z * v1.z + v1.w * v1.w;
#pragma unroll
    for (int m = 1; m < 64; m <<= 1) { sum += __shfl_xor(sum, m, 64); sq += __shfl_xor(sq, m, 64); }
    float mu = sum * (1.0f / LL);
    float var = sq * (1.0f / LL) - mu * mu;
    float rstd = rsqrtf(var + 1e-5f);
    const float* gp = g + lane * 8;
    const float* bp = be + lane * 8;
    float4 g0 = *(const float4*)gp, g1 = *(const float4*)(gp + 4);
    float4 b0 = *(const float4*)bp, b1 = *(const float4*)(bp + 4);
    float y0 = (v0.x - mu) * rstd * g0.x + b0.x;
    float y1 = (v0.y - mu) * rstd * g0.y + b0.y;
    float y2 = (v0.z - mu) * rstd * g0.z + b0.z;
    float y3 = (v0.w - mu) * rstd * g0.w + b0.w;
    float y4 = (v1.x - mu) * rstd * g1.x + b1.x;
    float y5 = (v1.y - mu) * rstd * g1.y + b1.y;
    float y6 = (v1.z - mu) * rstd * g1.z + b1.z;
    float y7 = (v1.w - mu) * rstd * g1.w + b1.w;
    long o = ((long)b * T + PAST + s) * LL + lane * 8;
    *(float4*)(cko + o) = make_float4(y0, y1, y2, y3);
    *(float4*)(cko + o + 4) = make_float4(y4, y5, y6, y7);
    *(ushort4*)(ckb + o) = make_ushort4(f2b(y0), f2b(y1), f2b(y2), f2b(y3));
    *(ushort4*)(ckb + o + 4) = make_ushort4(f2b(y4), f2b(y5), f2b(y6), f2b(y7));
}

// ---------------- generic NT GEMM (r15 version): C = cscale * A * B^T -------
template <bool OUT_BF16>
__global__ __launch_bounds__(256, 2) void gemm_nt(const ushort* __restrict__ A,
                                                  const ushort* __restrict__ B,
                                                  void* __restrict__ Cv,
                                                  int K, int lda, int ldb, int ldc,
                                                  long aHi, long aLo, long bHi, long bLo,
                                                  long cHi, long cLo, int zdiv, float cscale) {
    __shared__ __align__(16) ushort Asm[128 * 72];
    __shared__ __align__(16) ushort Bsm[128 * 72];
    const int tid = threadIdx.x, wid = tid >> 6, lane = tid & 63;
    const int z = blockIdx.z, zh = z / zdiv, zl = z % zdiv;
    A += zh * aHi + zl * aLo;
    B += zh * bHi + zl * bLo;
    const long cOff = zh * cHi + zl * cLo;
    const int m0 = blockIdx.x * 128, n0 = blockIdx.y * 128;
    const int wm = (wid >> 1) * 64, wn = (wid & 1) * 64;
    f32x4 acc[4][4] = {};
    const int l8 = lane & 7;
    const int rowA = wid * 8 + (lane >> 3);
    const ushort* Ag = A + (long)(m0 + rowA) * lda + l8 * 8;
    const ushort* Bg = B + (long)(n0 + rowA) * ldb + l8 * 8;

    i32x4 ra[4], rb[4];
#pragma unroll
    for (int p = 0; p < 4; ++p) {
        ra[p] = *(const i32x4*)(Ag + (long)p * 32 * lda);
        rb[p] = *(const i32x4*)(Bg + (long)p * 32 * ldb);
    }
    for (int kt = 0; kt < K; kt += 64) {
        __syncthreads();
#pragma unroll
        for (int p = 0; p < 4; ++p) {
            *(i32x4*)(Asm + (p * 32 + rowA) * 72 + l8 * 8) = ra[p];
            *(i32x4*)(Bsm + (p * 32 + rowA) * 72 + l8 * 8) = rb[p];
        }
        __syncthreads();
        if (kt + 64 < K) {
#pragma unroll
            for (int p = 0; p < 4; ++p) {
                ra[p] = *(const i32x4*)(Ag + (long)p * 32 * lda + kt + 64);
                rb[p] = *(const i32x4*)(Bg + (long)p * 32 * ldb + kt + 64);
            }
        }
#pragma unroll
        for (int kk = 0; kk < 2; ++kk) {
            const int ko = kk * 32 + ((lane >> 4) << 3);
            bf16x8 af[4], bf[4];
#pragma unroll
            for (int i = 0; i < 4; ++i)
                af[i] = *(const bf16x8*)(Asm + (wm + i * 16 + (lane & 15)) * 72 + ko);
#pragma unroll
            for (int j = 0; j < 4; ++j)
                bf[j] = *(const bf16x8*)(Bsm + (wn + j * 16 + (lane & 15)) * 72 + ko);
#pragma unroll
            for (int i = 0; i < 4; ++i)
#pragma unroll
                for (int j = 0; j < 4; ++j)
                    acc[i][j] = __builtin_amdgcn_mfma_f32_16x16x32_bf16(af[i], bf[j], acc[i][j], 0, 0, 0);
        }
        __syncthreads();
    }
    const int cr = (lane >> 4) * 4, cc = lane & 15;
#pragma unroll
    for (int i = 0; i < 4; ++i) {
#pragma unroll
        for (int r = 0; r < 4; ++r) {
            const long row = m0 + wm + i * 16 + cr + r;
#pragma unroll
            for (int j = 0; j < 4; ++j) {
                const long col = n0 + wn + j * 16 + cc;
                if (OUT_BF16)
                    ((ushort*)Cv)[cOff + row * ldc + col] = f2b(acc[i][j][r] * cscale);
                else
                    ((float*)Cv)[cOff + row * ldc + col] = acc[i][j][r] * cscale;
            }
        }
    }
}

// ---------------- fused pair GEMM: absb (bf16 out) + cpre (f32 out) ----------
__global__ __launch_bounds__(256, 2) void gemm_pair_k(const ushort* __restrict__ A0,
                                                      const ushort* __restrict__ B0,
                                                      ushort* __restrict__ C0,
                                                      const ushort* __restrict__ A1,
                                                      const ushort* __restrict__ B1,
                                                      float* __restrict__ C1,
                                                      float cs0) {
    __shared__ __align__(16) ushort Asm[128 * 72];
    __shared__ __align__(16) ushort Bsm[128 * 72];
    const int tid = threadIdx.x, wid = tid >> 6, lane = tid & 63;
    const int bx = (int)blockIdx.x;
    const bool p0 = (bx < 16);
    const ushort* A = p0 ? A0 : A1;
    const ushort* B = p0 ? B0 : B1;
    const int m0 = (p0 ? bx : bx - 16) * 128;
    const int n0 = blockIdx.y * 128;
    const float cs = p0 ? cs0 : 1.0f;
    f32x4 acc[4][4] = {};
    const int l8 = lane & 7;
    const int rowA = wid * 8 + (lane >> 3);
    const ushort* Ag = A + (long)(m0 + rowA) * DV + l8 * 8;
    const ushort* Bg = B + (long)(n0 + rowA) * DV + l8 * 8;

    i32x4 ra[4], rb[4];
#pragma unroll
    for (int p = 0; p < 4; ++p) {
        ra[p] = *(const i32x4*)(Ag + (long)p * 32 * DV);
        rb[p] = *(const i32x4*)(Bg + (long)p * 32 * DV);
    }
    for (int kt = 0; kt < DV; kt += 64) {
        __syncthreads();
#pragma unroll
        for (int p = 0; p < 4; ++p) {
            *(i32x4*)(Asm + (p * 32 + rowA) * 72 + l8 * 8) = ra[p];
            *(i32x4*)(Bsm + (p * 32 + rowA) * 72 + l8 * 8) = rb[p];
        }
        __syncthreads();
        if (kt + 64 < DV) {
#pragma unroll
            for (int p = 0; p < 4; ++p) {
                ra[p] = *(const i32x4*)(Ag + (long)p * 32 * DV + kt + 64);
                rb[p] = *(const i32x4*)(Bg + (long)p * 32 * DV + kt + 64);
            }
        }
#pragma unroll
        for (int kk = 0; kk < 2; ++kk) {
            const int ko = kk * 32 + ((lane >> 4) << 3);
            bf16x8 af[4], bf[4];
#pragma unroll
            for (int i = 0; i < 4; ++i)
                af[i] = *(const bf16x8*)(Asm + ((wid >> 1) * 64 + i * 16 + (lane & 15)) * 72 + ko);
#pragma unroll
            for (int j = 0; j < 4; ++j)
                bf[j] = *(const bf16x8*)(Bsm + ((wid & 1) * 64 + j * 16 + (lane & 15)) * 72 + ko);
#pragma unroll
            for (int i = 0; i < 4; ++i)
#pragma unroll
                for (int j = 0; j < 4; ++j)
                    acc[i][j] = __builtin_amdgcn_mfma_f32_16x16x32_bf16(af[i], bf[j], acc[i][j], 0, 0, 0);
        }
        __syncthreads();
    }
    const int wm = (wid >> 1) * 64, wn = (wid & 1) * 64;
    const int cr = (lane >> 4) * 4, cc = lane & 15;
#pragma unroll
    for (int i = 0; i < 4; ++i) {
#pragma unroll
        for (int r = 0; r < 4; ++r) {
            const long row = m0 + wm + i * 16 + cr + r;
#pragma unroll
            for (int j = 0; j < 4; ++j) {
                const long col = n0 + wn + j * 16 + cc;
                if (p0)
                    C0[row * LL + col] = f2b(acc[i][j][r] * cs);
                else
                    C1[row * LL + col] = acc[i][j][r];
            }
        }
    }
}

// ---------------- fused pair2 GEMM: Vt + khat (both K=512, bf16 out) ---------
// blocks 0..1023 -> Vt[b] = Wuv @ ckv[b]^T ([DV][T], ldc=T);
// blocks 1024..2047 -> khat[b] = ckv[b] @ absb^T ([T][DV], ldc=DV).
__global__ __launch_bounds__(256, 2) void gemm_pair2_k(const ushort* __restrict__ Wuvb,
                                                       const ushort* __restrict__ ckvb,
                                                       const ushort* __restrict__ absb,
                                                       ushort* __restrict__ vtb,
                                                       ushort* __restrict__ ktb,
                                                       int T) {
    __shared__ __align__(16) ushort Asm[128 * 72];
    __shared__ __align__(16) ushort Bsm[128 * 72];
    const int tid = threadIdx.x, wid = tid >> 6, lane = tid & 63;
    int bx = (int)blockIdx.x;
    const bool p0 = (bx < 1024);
    if (!p0) bx -= 1024;
    const int z = bx >> 9;
    const int r9 = bx & 511;
    const ushort* A;
    const ushort* B;
    ushort* C;
    int m0, n0, ldc;
    if (p0) {                       // Vt: m over DV (16), n over T (32)
        m0 = (r9 & 15) * 128;
        n0 = (r9 >> 4) * 128;
        A = Wuvb;
        B = ckvb + (long)z * T * LL;
        C = vtb + (long)z * DV * T;
        ldc = T;
    } else {                        // khat: m over T (32), n over DV (16)
        m0 = (r9 >> 4) * 128;
        n0 = (r9 & 15) * 128;
        A = ckvb + (long)z * T * LL;
        B = absb;
        C = ktb + (long)z * T * DV;
        ldc = DV;
    }
    f32x4 acc[4][4] = {};
    const int l8 = lane & 7;
    const int rowA = wid * 8 + (lane >> 3);
    const ushort* Ag = A + (long)(m0 + rowA) * LL + l8 * 8;
    const ushort* Bg = B + (long)(n0 + rowA) * LL + l8 * 8;

    i32x4 ra[4], rb[4];
#pragma unroll
    for (int p = 0; p < 4; ++p) {
        ra[p] = *(const i32x4*)(Ag + (long)p * 32 * LL);
        rb[p] = *(const i32x4*)(Bg + (long)p * 32 * LL);
    }
    for (int kt = 0; kt < LL; kt += 64) {
        __syncthreads();
#pragma unroll
        for (int p = 0; p < 4; ++p) {
            *(i32x4*)(Asm + (p * 32 + rowA) * 72 + l8 * 8) = ra[p];
            *(i32x4*)(Bsm + (p * 32 + rowA) * 72 + l8 * 8) = rb[p];
        }
        __syncthreads();
        if (kt + 64 < LL) {
#pragma unroll
            for (int p = 0; p < 4; ++p) {
                ra[p] = *(const i32x4*)(Ag + (long)p * 32 * LL + kt + 64);
                rb[p] = *(const i32x4*)(Bg + (long)p * 32 * LL + kt + 64);
            }
        }
#pragma unroll
        for (int kk = 0; kk < 2; ++kk) {
            const int ko = kk * 32 + ((lane >> 4) << 3);
            bf16x8 af[4], bf[4];
#pragma unroll
            for (int i = 0; i < 4; ++i)
                af[i] = *(const bf16x8*)(Asm + ((wid >> 1) * 64 + i * 16 + (lane & 15)) * 72 + ko);
#pragma unroll
            for (int j = 0; j < 4; ++j)
                bf[j] = *(const bf16x8*)(Bsm + ((wid & 1) * 64 + j * 16 + (lane & 15)) * 72 + ko);
#pragma unroll
            for (int i = 0; i < 4; ++i)
#pragma unroll
                for (int j = 0; j < 4; ++j)
                    acc[i][j] = __builtin_amdgcn_mfma_f32_16x16x32_bf16(af[i], bf[j], acc[i][j], 0, 0, 0);
        }
        __syncthreads();
    }
    const int wm = (wid >> 1) * 64, wn = (wid & 1) * 64;
    const int cr = (lane >> 4) * 4, cc = lane & 15;
#pragma unroll
    for (int i = 0; i < 4; ++i) {
#pragma unroll
        for (int r = 0; r < 4; ++r) {
            const long row = m0 + wm + i * 16 + cr + r;
#pragma unroll
            for (int j = 0; j < 4; ++j) {
                const long col = n0 + wn + j * 16 + cc;
                C[row * (long)ldc + col] = f2b(acc[i][j][r]);
            }
        }
    }
}

// ---------------- flash attention (r17, unchanged) ---------------------------
#define PH_WAIT4()                                               \
    do {                                                         \
        asm volatile("s_waitcnt vmcnt(4) lgkmcnt(0)" ::: "memory"); \
        __builtin_amdgcn_s_barrier();                            \
    } while (0)
#define PH_WAIT0()                                               \
    do {                                                         \
        asm volatile("s_waitcnt vmcnt(0) lgkmcnt(0)" ::: "memory"); \
        __builtin_amdgcn_s_barrier();                            \
    } while (0)
#define RD_BAR()                                                 \
    do {                                                         \
        asm volatile("s_waitcnt lgkmcnt(0)" ::: "memory");       \
        __builtin_amdgcn_s_barrier();                            \
    } while (0)

__global__ __launch_bounds__(256, 4) void attn_k(const ushort* __restrict__ qbf,
                                                 const ushort* __restrict__ ktb,
                                                 const ushort* __restrict__ vtb,
                                                 ushort* __restrict__ ctxb,
                                                 int S, int T, int PAST) {
    __shared__ __align__(16) ushort bufK[64 * 128];   // [t][d], 4-bit XOR-swizzled cols
    __shared__ __align__(16) ushort bufV[128 * 64];   // [d][t], 3-bit XOR-swizzled cols
    __shared__ __align__(16) ushort pl[4][16][64];    // per-wave P [q][t], t XOR-swizzled
    const int tid = threadIdx.x, wid = tid >> 6, lane = tid & 63;
    // chunked XCD mapping + per-CU length balancing
    const int nsb = S >> 6;               // 32
    const int nwg = BB * HH * nsb;        // 1024
    const int cpx = nwg >> 3;             // 128
    const int id = (int)blockIdx.x;
    const int xcd = id & 7, k = id >> 3;
    const int r4 = k >> 5, c32 = k & 31;
    const int local = r4 * 32 + ((c32 + r4 * 8) & 31);
    const int orig = xcd * cpx + local;
    const int sblk = orig % nsb;
    const int h = (orig / nsb) % HH;
    const int b = orig / (nsb * HH);
    const int s0 = (nsb - 1 - sblk) * 64;  // longest-first within chunk

    const int g = lane >> 4, l15 = lane & 15, q8 = g << 3;
    const int swr = (l15 & 7) << 3;   // 3-bit read XOR (bufV / pl)
    const int swrK = l15 << 3;        // 4-bit read XOR (bufK)

    // Q fragments: per-head slice of x (scale*log2e folded into khat)
    bf16x8 qf[4];
    {
        const ushort* qb = qbf + ((long)b * S + s0 + wid * 16 + l15) * DV + h * DHD + q8;
#pragma unroll
        for (int kk = 0; kk < 4; ++kk) qf[kk] = *(const bf16x8*)(qb + kk * 32);
    }
    f32x4 cacc[8] = {};
    f32x4 sacc[4] = {};   // swapped: sacc[nf][r] = S[t = nf*16+g*4+r][q = l15] (log2 domain)
    float mrow = -1e30f, lrow = 0.f;  // per-lane, q = wid*16 + l15
    const int rl = tid >> 4, cc16 = tid & 15;
    const int vr = tid >> 3, vc = tid & 7;
    const int nfull = (s0 + PAST) / 64;
    const ushort* kbase = ktb + (long)b * T * DV + h * DHD;
    const ushort* vbase = vtb + ((long)b * DV + h * DHD) * T;
    const int kcol = (cc16 ^ rl) << 3;        // 4-bit pre-swizzled K source col
    const int vcol = (vc ^ (vr & 7)) << 3;    // 3-bit pre-swizzled V source col

    auto stageK = [&](int tt_) {
#pragma unroll
        for (int p = 0; p < 4; ++p)
            gll16(kbase + (long)(tt_ * 64 + p * 16 + rl) * DV + kcol, &bufK[p * 2048 + tid * 8]);
    };
    auto stageV = [&](int tt_) {
#pragma unroll
        for (int p = 0; p < 4; ++p)
            gll16(vbase + (long)(p * 32 + vr) * T + tt_ * 64 + vcol, &bufV[p * 2048 + tid * 8]);
    };

    stageK(0);
    stageV(0);

    for (int tt = 0; tt <= nfull; ++tt) {
        const bool last = (tt == nfull);
        // ---- phase A: wait K(tt); QK (swapped: out[t][q]) ----
        PH_WAIT4();
        __builtin_amdgcn_s_setprio(1);
#pragma unroll
        for (int kk = 0; kk < 4; ++kk) {
            const int ko = kk * 32 + q8;
#pragma unroll
            for (int nf = 0; nf < 4; ++nf) {
                bf16x8 af = *(const bf16x8*)(&bufK[(nf * 16 + l15) * 128 + (ko ^ swrK)]);
                sacc[nf] = __builtin_amdgcn_mfma_f32_16x16x32_bf16(af, qf[kk], sacc[nf], 0, 0, 0);
            }
        }
        __builtin_amdgcn_s_setprio(0);
        RD_BAR();                       // all waves done reading bufK
        if (!last) stageK(tt + 1);      // overwrite bufK with next K
        // ---- phase B: wait V(tt); softmax + PV ----
        if (last) { PH_WAIT0(); } else { PH_WAIT4(); }
        float pm = -1e30f;
#pragma unroll
        for (int nf = 0; nf < 4; ++nf)
#pragma unroll
            for (int r = 0; r < 4; ++r) {
                float v = sacc[nf][r];
                if (last) {
                    int tl = nf * 16 + (g << 2) + r;
                    int ql = wid * 16 + l15;
                    if (tl > ql) v = -1e30f;
                }
                sacc[nf][r] = v;
                pm = fmaxf(pm, v);
            }
        pm = fmaxf(pm, __shfl_xor(pm, 16, 64));
        pm = fmaxf(pm, __shfl_xor(pm, 32, 64));
        if (__any(pm > mrow + 11.5f)) {
            float mn = fmaxf(mrow, pm);
            float al = EX2(mrow - mn);
            mrow = mn;
            lrow *= al;
#pragma unroll
            for (int r = 0; r < 4; ++r) {
                float alr = __shfl(al, (g << 2) + r, 64);  // al for q-row g*4+r
#pragma unroll
                for (int df = 0; df < 8; ++df) cacc[df][r] *= alr;
            }
        }
        float ps = 0.f;
#pragma unroll
        for (int nf = 0; nf < 4; ++nf)
#pragma unroll
            for (int r = 0; r < 4; ++r) {
                float p = EX2(sacc[nf][r] - mrow);
                sacc[nf][r] = p;
                ps += p;
            }
        ps += __shfl_xor(ps, 16, 64);
        ps += __shfl_xor(ps, 32, 64);
        lrow += ps;
        // P -> wave-private swizzled LDS: packed pairs (t even; bit0 unaffected by swr)
#pragma unroll
        for (int nf = 0; nf < 4; ++nf)
#pragma unroll
            for (int rp = 0; rp < 2; ++rp) {
                unsigned int hb = cvt_pk_bf16(sacc[nf][rp * 2], sacc[nf][rp * 2 + 1]);
                const int tlo = nf * 16 + (g << 2) + rp * 2;
                *(unsigned int*)&pl[wid][l15][tlo ^ swr] = hb;
            }
#pragma unroll
        for (int nf = 0; nf < 4; ++nf) sacc[nf] = (f32x4){0.f, 0.f, 0.f, 0.f};
        // ctx += P * V
        __builtin_amdgcn_s_setprio(1);
#pragma unroll
        for (int kk = 0; kk < 2; ++kk) {
            bf16x8 a = *(const bf16x8*)(&pl[wid][l15][(kk * 32 + q8) ^ swr]);
#pragma unroll
            for (int df = 0; df < 8; ++df) {
                bf16x8 bv = *(const bf16x8*)(&bufV[(df * 16 + l15) * 64 + ((kk * 32 + q8) ^ swr)]);
                cacc[df] = __builtin_amdgcn_mfma_f32_16x16x32_bf16(a, bv, cacc[df], 0, 0, 0);
            }
        }
        __builtin_amdgcn_s_setprio(0);
        if (!last) {
            RD_BAR();                   // all waves done reading bufV
            stageV(tt + 1);
        }
    }
    // ---- epilogue ----
    const long rbase = (long)b * S + s0 + wid * 16 + (g << 2);
#pragma unroll
    for (int r = 0; r < 4; ++r) {
        float lr = __shfl(lrow, (g << 2) + r, 64);
        float inv = 1.0f / lr;
        const int d = h * DHD + l15;
#pragma unroll
        for (int df = 0; df < 8; ++df)
            ctxb[(rbase + r) * DV + d + df * 16] = f2b(cacc[df][r] * inv);
    }
}

extern "C" void kernel_launch(void* const* d_in, const int* in_sizes, int n_in,
                              void* d_out, int out_size, void* d_ws, size_t ws_size,
                              hipStream_t stream) {
    const float* x = (const float*)d_in[0];
    const float* kv = (const float*)d_in[1];
    const float* Wq = (const float*)d_in[2];
    const float* Wdkv = (const float*)d_in[3];
    const float* Wuk = (const float*)d_in[4];
    const float* Wuv = (const float*)d_in[5];
    const float* Wo = (const float*)d_in[6];
    const float* lng = (const float*)d_in[7];
    const float* lnbt = (const float*)d_in[8];
    const int S = in_sizes[0] / (BB * DV);     // 2048
    const int PAST = in_sizes[1] / (BB * LL);  // 2048
    const int T = S + PAST;                    // 4096

    float* out_p = (float*)d_out;                       // [B,S,D] f32
    float* ckv_out = out_p + (size_t)BB * S * DV;       // [B,T,L] f32

    char* w = (char*)d_ws;
    auto take = [&](size_t bytes) { char* p = w; w += (bytes + 255) & ~(size_t)255; return p; };
    ushort* xb    = (ushort*)take((size_t)BB * S * DV * 2);
    ushort* Wqb   = (ushort*)take((size_t)DV * DV * 2);
    ushort* WukT  = (ushort*)take((size_t)DV * LL * 2);   // [L][D] = Wuk^T
    ushort* Wdkvb = (ushort*)take((size_t)LL * DV * 2);
    ushort* Wuvb  = (ushort*)take((size_t)DV * LL * 2);
    ushort* Wob   = (ushort*)take((size_t)DV * DV * 2);
    ushort* absb  = (ushort*)take((size_t)DV * LL * 2);   // [D][L] = Wq@Wuk (scaled*log2e)
    float*  cpre  = (float*)take((size_t)BB * S * LL * 4);
    ushort* ckvb  = (ushort*)take((size_t)BB * T * LL * 2);
    ushort* vtb   = (ushort*)take((size_t)BB * DV * T * 2);  // [B][D][T]
    ushort* ktb   = (ushort*)take((size_t)BB * T * DV * 2);  // [B][T][D] khat
    ushort* ctxb  = (ushort*)take((size_t)BB * S * DV * 2);

    // fused f32->bf16 conversion of all 5 weight/activation tensors
    cvt5_k<<<dim3(2048), dim3(256), 0, stream>>>(
        x, xb, (long)BB * S * DV,
        Wq, Wqb, (long)DV * DV,
        Wdkv, Wdkvb, (long)LL * DV,
        Wuv, Wuvb, (long)DV * LL,
        Wo, Wob, (long)DV * DV);
    transpose_cvt_k<<<dim3(LL / 64, DV / 64), dim3(256), 0, stream>>>(Wuk, WukT, DV, LL);
    kvcopy_k<<<dim3(2048), dim3(256), 0, stream>>>(kv, ckv_out, ckvb, PAST, T);

    // fused: absb = log2e/sqrt(dh) * Wq @ Wuk   AND   cpre = x @ Wdkv^T (f32)
    gemm_pair_k<<<dim3(48, LL / 128), dim3(256), 0, stream>>>(
        Wqb, WukT, absb, xb, Wdkvb, cpre, 0.12751744900014818f);
    ln_k<<<dim3(BB * S / 4), dim3(256), 0, stream>>>(cpre, lng, lnbt, ckv_out, ckvb, S, PAST, T);
    // fused: Vt[b] = Wuv @ ckv[b]^T  AND  khat[b] = ckv[b] @ absb^T
    gemm_pair2_k<<<dim3(2048), dim3(256), 0, stream>>>(Wuvb, ckvb, absb, vtb, ktb, T);
    // attention (d=128 MHA; Q = per-head slice of x)
    attn_k<<<dim3(BB * HH * (S / 64)), dim3(256), 0, stream>>>(xb, ktb, vtb, ctxb, S, T, PAST);
    // out = ctx * Wo^T (f32)
    gemm_nt<false><<<dim3(BB * S / 128, DV / 128, 1), dim3(256), 0, stream>>>(
        ctxb, Wob, out_p, DV, DV, DV, DV, 0, 0, 0, 0, 0, 0, 1, 1.0f);
}